// Round 1
// baseline (10703.898 us; speedup 1.0000x reference)
//
#include <hip/hip_runtime.h>

typedef unsigned short us_t;

#define E_ACT 200000
#define E_TOT 250000
#define DIR   240
#define C_OLD 0.8944271909999159f
#define C_NEW 0.4472135954999579f
#define S_OH  0.08838834764831845f   // 1/sqrt(128)

__device__ __forceinline__ float b2f(us_t u) { return __uint_as_float(((unsigned)u) << 16); }
__device__ __forceinline__ us_t f2b(float f) {
    unsigned x = __float_as_uint(f);
    return (us_t)((x + 0x7fffu + ((x >> 16) & 1u)) >> 16);   // RNE
}
__device__ __forceinline__ float sigm(float x) { return 1.0f / (1.0f + __expf(-x)); }
__device__ __forceinline__ void unpack8(uint4 v, float* a) {
    a[0] = __uint_as_float(v.x << 16); a[1] = __uint_as_float(v.x & 0xffff0000u);
    a[2] = __uint_as_float(v.y << 16); a[3] = __uint_as_float(v.y & 0xffff0000u);
    a[4] = __uint_as_float(v.z << 16); a[5] = __uint_as_float(v.z & 0xffff0000u);
    a[6] = __uint_as_float(v.w << 16); a[7] = __uint_as_float(v.w & 0xffff0000u);
}

// ============================================================================
// K1: gather + Wigner rotations + stage-1 GEMMs (W0, W1r/i, W2r/i, Gw, Ew)
//     + gating + y-build + D^T rotations + gates/silu + P0/P1/P2 + w-scale
//     + LayerNorm.  Writes: new_edge (f32), [ln_lat|scalars] (bf16).
//     16 edges / 256-thread block.
// ============================================================================
__global__ __launch_bounds__(256) void k1_kernel(
    const float* __restrict__ latents,
    const float* __restrict__ node_features,
    const float* __restrict__ edge_features,
    const float* __restrict__ wD1,
    const float* __restrict__ wD2,
    const float* __restrict__ W0,
    const float* __restrict__ W1r, const float* __restrict__ W1i,
    const float* __restrict__ W2r, const float* __restrict__ W2i,
    const float* __restrict__ Gw,  const float* __restrict__ Gb,
    const float* __restrict__ P0w, const float* __restrict__ P0b,
    const float* __restrict__ P1w, const float* __restrict__ P2w,
    const float* __restrict__ Ew,  const float* __restrict__ Eb,
    const float* __restrict__ ln_g, const float* __restrict__ ln_b,
    const int* __restrict__ edge_index, const int* __restrict__ active_edges,
    float* __restrict__ ne_ws, us_t* __restrict__ lnscal_ws)
{
    __shared__ __align__(16) char smem[58560];
    // act region (bf16), aliased by z-buffers (f32) in phase C
    us_t* in0s = (us_t*)(smem);          // [16][344]  (336 used)
    us_t* ip1s = (us_t*)(smem + 11008);  // [16][152]  (144 used)
    us_t* im1s = (us_t*)(smem + 15872);  // [16][152]
    us_t* r24s = (us_t*)(smem + 20736);  // [16][56]   (48 used)
    us_t* r20s = (us_t*)(smem + 22528);  // [16][56]
    float* z1l = (float*)(smem);         // [16][100]  (96 used)   alias act
    float* z2l = (float*)(smem + 6400);  // [16][84]   (80 used)   alias act
    float* z0l = (float*)(smem + 11776); // [16][68]   (64 used)   alias act
    float* latl = (float*)(smem + 24320);// [16][132]  (128 used)
    float* D1l  = (float*)(smem + 32768);// [16][12]   (9 used)
    float* D2l  = (float*)(smem + 33536);// [16][28]   (25 used)
    // union2: phase-A raw staging (bf16), then GEMM outputs (bf16)
    us_t* stg  = (us_t*)(smem + 35328);  // [3][16][242]
    us_t* om0g = (us_t*)(smem + 35328);  // [16][164]  (160 used, gated)
    us_t* op1l = (us_t*)(smem + 40576);  // [16][52]
    us_t* on1l = (us_t*)(smem + 42240);  // [16][52]
    us_t* op2l = (us_t*)(smem + 43904);  // [16][20]
    us_t* on2l = (us_t*)(smem + 44544);  // [16][20]
    us_t* gl   = (us_t*)(smem + 45184);  // [16][228]  (224 used)
    us_t* wl   = (us_t*)(smem + 52480);  // [16][116]  (112 used)

    const int t  = threadIdx.x;
    const int e0 = blockIdx.x * 16;

    // ---------------- Phase A: loads ----------------
    {
        const int e = t >> 4, l = t & 15;
        const int eg = e0 + e;
        const int ae = active_edges[eg];
        const int ec = edge_index[ae];
        const int en = edge_index[E_TOT + ae];
        const float* nfc = node_features + (size_t)ec * DIR;
        const float* nfn = node_features + (size_t)en * DIR;
        const float* efp = edge_features + (size_t)eg * DIR;
        us_t* s_nfc = stg + (0 * 16 + e) * 242;
        us_t* s_ef  = stg + (1 * 16 + e) * 242;
        us_t* s_nfn = stg + (2 * 16 + e) * 242;
        for (int i = l; i < DIR; i += 16) {
            s_nfc[i] = f2b(nfc[i]);
            s_ef[i]  = f2b(efp[i]);
            s_nfn[i] = f2b(nfn[i]);
        }
        for (int i = l; i < 128; i += 16) latl[e * 132 + i] = latents[(size_t)ae * 128 + i];
        if (l < 9) D1l[e * 12 + l] = wD1[(size_t)eg * 9 + l];
        D2l[e * 28 + l] = wD2[(size_t)eg * 25 + l];
        if (l < 9) D2l[e * 28 + 16 + l] = wD2[(size_t)eg * 25 + 16 + l];
    }
    __syncthreads();

    // ---------------- Phase A2: build activations (x0, r1, r2) ----------------
    {
        const int e = t >> 4, l = t & 15;
        const us_t* s_nfc = stg + (0 * 16 + e) * 242;
        const us_t* s_ef  = stg + (1 * 16 + e) * 242;
        const us_t* s_nfn = stg + (2 * 16 + e) * 242;
        us_t* in0 = in0s + e * 344;
        us_t* ip1 = ip1s + e * 152;
        us_t* im1 = im1s + e * 152;
        for (int i = l; i < 64; i += 16) {
            in0[i]       = s_nfc[i];
            in0[64 + i]  = s_ef[i];
            in0[128 + i] = s_nfn[i];
        }
        const float* D1e = D1l + e * 12;
        for (int u = l; u < 96; u += 16) {
            const us_t* src; int base;
            if (u < 32)      { src = s_nfc; base = 64 + u * 3; }
            else if (u < 64) { src = s_ef;  base = 64 + (u - 32) * 3; }
            else             { src = s_nfn; base = 64 + (u - 64) * 3; }
            float x0 = b2f(src[base]), x1 = b2f(src[base + 1]), x2 = b2f(src[base + 2]);
            float r0 = D1e[0] * x0 + D1e[1] * x1 + D1e[2] * x2;   // i=0
            float r1 = D1e[3] * x0 + D1e[4] * x1 + D1e[5] * x2;   // i=1
            float r2 = D1e[6] * x0 + D1e[7] * x1 + D1e[8] * x2;   // i=2
            im1[u]       = f2b(r0);
            in0[192 + u] = f2b(r1);
            ip1[u]       = f2b(r2);
        }
        const float* D2e = D2l + e * 28;
        for (int u = l; u < 48; u += 16) {
            const us_t* src; int base;
            if (u < 16)      { src = s_nfc; base = 160 + u * 5; }
            else if (u < 32) { src = s_ef;  base = 160 + (u - 16) * 5; }
            else             { src = s_nfn; base = 160 + (u - 32) * 5; }
            float x0 = b2f(src[base]),     x1 = b2f(src[base + 1]), x2 = b2f(src[base + 2]);
            float x3 = b2f(src[base + 3]), x4 = b2f(src[base + 4]);
            float r[5];
            #pragma unroll
            for (int i = 0; i < 5; ++i)
                r[i] = D2e[i * 5 + 0] * x0 + D2e[i * 5 + 1] * x1 + D2e[i * 5 + 2] * x2
                     + D2e[i * 5 + 3] * x3 + D2e[i * 5 + 4] * x4;
            r20s[e * 56 + u] = f2b(r[0]);
            im1[96 + u]      = f2b(r[1]);
            in0[288 + u]     = f2b(r[2]);
            ip1[96 + u]      = f2b(r[3]);
            r24s[e * 56 + u] = f2b(r[4]);
        }
    }
    __syncthreads();

    // ---------------- Phase B1: g = lat@Gw+Gb (224), w = lat@Ew+Eb (112) ----------------
    {
        const int e = t & 15, q = t >> 4;
        float4 accg[4], accw[2];
        #pragma unroll
        for (int j = 0; j < 4; ++j) {
            int n = q * 4 + 64 * j;
            accg[j] = make_float4(0.f, 0.f, 0.f, 0.f);
            if (n < 224) accg[j] = *(const float4*)&Gb[n];
        }
        #pragma unroll
        for (int j = 0; j < 2; ++j) {
            int n = q * 4 + 64 * j;
            accw[j] = make_float4(0.f, 0.f, 0.f, 0.f);
            if (n < 112) accw[j] = *(const float4*)&Eb[n];
        }
        for (int k = 0; k < 128; k += 4) {
            float4 a4 = *(const float4*)&latl[e * 132 + k];
            float aa[4] = {a4.x, a4.y, a4.z, a4.w};
            #pragma unroll
            for (int kk = 0; kk < 4; ++kk) {
                float a = aa[kk];
                #pragma unroll
                for (int j = 0; j < 4; ++j) {
                    int n = q * 4 + 64 * j;
                    if (n < 224) {
                        float4 wv = *(const float4*)&Gw[(k + kk) * 224 + n];
                        accg[j].x += a * wv.x; accg[j].y += a * wv.y;
                        accg[j].z += a * wv.z; accg[j].w += a * wv.w;
                    }
                }
                #pragma unroll
                for (int j = 0; j < 2; ++j) {
                    int n = q * 4 + 64 * j;
                    if (n < 112) {
                        float4 wv = *(const float4*)&Ew[(k + kk) * 112 + n];
                        accw[j].x += a * wv.x; accw[j].y += a * wv.y;
                        accw[j].z += a * wv.z; accw[j].w += a * wv.w;
                    }
                }
            }
        }
        #pragma unroll
        for (int j = 0; j < 4; ++j) {
            int n = q * 4 + 64 * j;
            if (n < 224) {
                ushort4 s; s.x = f2b(accg[j].x); s.y = f2b(accg[j].y);
                s.z = f2b(accg[j].z); s.w = f2b(accg[j].w);
                *(ushort4*)&gl[e * 228 + n] = s;
            }
        }
        #pragma unroll
        for (int j = 0; j < 2; ++j) {
            int n = q * 4 + 64 * j;
            if (n < 112) {
                ushort4 s; s.x = f2b(accw[j].x); s.y = f2b(accw[j].y);
                s.z = f2b(accw[j].z); s.w = f2b(accw[j].w);
                *(ushort4*)&wl[e * 116 + n] = s;
            }
        }
    }
    __syncthreads();

    // ---------------- Phase B2: o_m0 / op1 / on1 / op2 / on2 (gated) ----------------
    {
        const int e = t & 15, q = t >> 4;
        // o_m0 (160) = in0(336) @ W0^T, gated by g[:160]
        {
            float acc[10];
            #pragma unroll
            for (int j = 0; j < 10; ++j) acc[j] = 0.f;
            for (int k = 0; k < 336; k += 8) {
                uint4 av = *(const uint4*)&in0s[e * 344 + k];
                float a[8]; unpack8(av, a);
                #pragma unroll
                for (int j = 0; j < 10; ++j) {
                    const float* wr = W0 + (size_t)(q + 16 * j) * 336 + k;
                    float4 w0 = *(const float4*)wr;
                    float4 w1 = *(const float4*)(wr + 4);
                    acc[j] += a[0] * w0.x + a[1] * w0.y + a[2] * w0.z + a[3] * w0.w
                            + a[4] * w1.x + a[5] * w1.y + a[6] * w1.z + a[7] * w1.w;
                }
            }
            #pragma unroll
            for (int j = 0; j < 10; ++j) {
                int n = q + 16 * j;
                om0g[e * 164 + n] = f2b(acc[j] * b2f(gl[e * 228 + n]));
            }
        }
        // op1/on1 (48 each): ip1/im1 (144) with W1r/W1i, gated by g[160:208]
        {
            float ap[3] = {0.f, 0.f, 0.f}, an[3] = {0.f, 0.f, 0.f};
            for (int k = 0; k < 144; k += 8) {
                uint4 pv = *(const uint4*)&ip1s[e * 152 + k];
                uint4 mv = *(const uint4*)&im1s[e * 152 + k];
                float p[8], m[8]; unpack8(pv, p); unpack8(mv, m);
                #pragma unroll
                for (int j = 0; j < 3; ++j) {
                    int n = q + 16 * j;
                    const float* wrp = W1r + (size_t)n * 144 + k;
                    const float* wip = W1i + (size_t)n * 144 + k;
                    float4 wr0 = *(const float4*)wrp, wr1 = *(const float4*)(wrp + 4);
                    float4 wi0 = *(const float4*)wip, wi1 = *(const float4*)(wip + 4);
                    float wr[8] = {wr0.x, wr0.y, wr0.z, wr0.w, wr1.x, wr1.y, wr1.z, wr1.w};
                    float wi[8] = {wi0.x, wi0.y, wi0.z, wi0.w, wi1.x, wi1.y, wi1.z, wi1.w};
                    #pragma unroll
                    for (int kk = 0; kk < 8; ++kk) {
                        ap[j] = fmaf(p[kk], wr[kk], ap[j]);
                        ap[j] = fmaf(-m[kk], wi[kk], ap[j]);
                        an[j] = fmaf(p[kk], wi[kk], an[j]);
                        an[j] = fmaf(m[kk], wr[kk], an[j]);
                    }
                }
            }
            #pragma unroll
            for (int j = 0; j < 3; ++j) {
                int n = q + 16 * j;
                float gg = b2f(gl[e * 228 + 160 + n]);
                op1l[e * 52 + n] = f2b(ap[j] * gg);
                on1l[e * 52 + n] = f2b(an[j] * gg);
            }
        }
        // op2/on2 (16 each): r24/r20 (48) with W2r/W2i, gated by g[208:224]
        {
            float ap2 = 0.f, an2 = 0.f;
            for (int k = 0; k < 48; k += 8) {
                uint4 pv = *(const uint4*)&r24s[e * 56 + k];
                uint4 mv = *(const uint4*)&r20s[e * 56 + k];
                float p[8], m[8]; unpack8(pv, p); unpack8(mv, m);
                const float* wrp = W2r + (size_t)q * 48 + k;
                const float* wip = W2i + (size_t)q * 48 + k;
                float4 wr0 = *(const float4*)wrp, wr1 = *(const float4*)(wrp + 4);
                float4 wi0 = *(const float4*)wip, wi1 = *(const float4*)(wip + 4);
                float wr[8] = {wr0.x, wr0.y, wr0.z, wr0.w, wr1.x, wr1.y, wr1.z, wr1.w};
                float wi[8] = {wi0.x, wi0.y, wi0.z, wi0.w, wi1.x, wi1.y, wi1.z, wi1.w};
                #pragma unroll
                for (int kk = 0; kk < 8; ++kk) {
                    ap2 = fmaf(p[kk], wr[kk], ap2);
                    ap2 = fmaf(-m[kk], wi[kk], ap2);
                    an2 = fmaf(p[kk], wi[kk], an2);
                    an2 = fmaf(m[kk], wr[kk], an2);
                }
            }
            float gg = b2f(gl[e * 228 + 208 + q]);
            op2l[e * 20 + q] = f2b(ap2 * gg);
            on2l[e * 20 + q] = f2b(an2 * gg);
        }
    }
    __syncthreads();

    // ---------------- Phase C1: y-build + D^T rotations + gates + silu ----------------
    {
        const int e = t >> 4, l = t & 15;
        const float* D1e = D1l + e * 12;
        const float* D2e = D2l + e * 28;
        #pragma unroll
        for (int uu = 0; uu < 2; ++uu) {
            int u = l + uu * 16;
            float j0 = b2f(on1l[e * 52 + u]);
            float j1 = b2f(om0g[e * 164 + 112 + u]);
            float j2 = b2f(op1l[e * 52 + u]);
            float gate = sigm(b2f(om0g[e * 164 + 64 + u]));
            #pragma unroll
            for (int i = 0; i < 3; ++i) {
                float yr = D1e[0 * 3 + i] * j0 + D1e[1 * 3 + i] * j1 + D1e[2 * 3 + i] * j2;
                z1l[e * 100 + u * 3 + i] = yr * gate;
            }
        }
        {
            int u = l;
            float j0 = b2f(on2l[e * 20 + u]);
            float j1 = b2f(on1l[e * 52 + 32 + u]);
            float j2 = b2f(om0g[e * 164 + 144 + u]);
            float j3 = b2f(op1l[e * 52 + 32 + u]);
            float j4 = b2f(op2l[e * 20 + u]);
            float gate = sigm(b2f(om0g[e * 164 + 96 + u]));
            #pragma unroll
            for (int i = 0; i < 5; ++i) {
                float yr = D2e[0 * 5 + i] * j0 + D2e[1 * 5 + i] * j1 + D2e[2 * 5 + i] * j2
                         + D2e[3 * 5 + i] * j3 + D2e[4 * 5 + i] * j4;
                z2l[e * 84 + u * 5 + i] = yr * gate;
            }
        }
        #pragma unroll
        for (int ii = 0; ii < 4; ++ii) {
            int c = l + 16 * ii;
            float v = b2f(om0g[e * 164 + c]);
            z0l[e * 68 + c] = v * sigm(v);
        }
    }
    __syncthreads();

    // ---------------- Phase C2: P0/P1/P2 + w-scale + scalars + LayerNorm ----------------
    {
        const int e = t >> 4, l = t & 15;
        const int eg = e0 + e;
        // P0 (64x64): scalars + ne[0:64)
        #pragma unroll
        for (int j = 0; j < 4; ++j) {
            int n = l + 16 * j;
            float acc = 0.f;
            for (int k = 0; k < 64; k += 4) {
                float4 zv = *(const float4*)&z0l[e * 68 + k];
                float4 pw = *(const float4*)&P0w[n * 64 + k];
                acc += zv.x * pw.x + zv.y * pw.y + zv.z * pw.z + zv.w * pw.w;
            }
            float z0p = acc * 0.125f + P0b[n];
            lnscal_ws[(size_t)eg * 192 + 128 + n] = f2b(z0p);
            ne_ws[(size_t)eg * 240 + n] = z0p * b2f(wl[e * 116 + n]);
        }
        // P1 (32x32) applied to z1 (32,3)
        #pragma unroll
        for (int uu = 0; uu < 2; ++uu) {
            int u = l + uu * 16;
            float wv = b2f(wl[e * 116 + 64 + u]);
            #pragma unroll
            for (int m = 0; m < 3; ++m) {
                float acc = 0.f;
                for (int v = 0; v < 32; ++v)
                    acc += P1w[u * 32 + v] * z1l[e * 100 + v * 3 + m];
                ne_ws[(size_t)eg * 240 + 64 + u * 3 + m] = acc * 0.17677669529663687f * wv;
            }
        }
        // P2 (16x16) applied to z2 (16,5)
        {
            int u = l;
            float wv = b2f(wl[e * 116 + 96 + u]);
            #pragma unroll
            for (int m = 0; m < 5; ++m) {
                float acc = 0.f;
                for (int v = 0; v < 16; ++v)
                    acc += P2w[u * 16 + v] * z2l[e * 84 + v * 5 + m];
                ne_ws[(size_t)eg * 240 + 160 + u * 5 + m] = acc * 0.25f * wv;
            }
        }
        // LayerNorm over lat row (128), 16 lanes per edge
        float s1 = 0.f, s2 = 0.f;
        #pragma unroll
        for (int i = 0; i < 8; ++i) {
            float v = latl[e * 132 + l * 8 + i];
            s1 += v; s2 += v * v;
        }
        #pragma unroll
        for (int off = 1; off < 16; off <<= 1) {
            s1 += __shfl_xor(s1, off, 16);
            s2 += __shfl_xor(s2, off, 16);
        }
        float mu  = s1 * (1.f / 128.f);
        float var = s2 * (1.f / 128.f) - mu * mu;
        float rstd = rsqrtf(var + 1e-5f);
        #pragma unroll
        for (int i = 0; i < 8; ++i) {
            int li = l * 8 + i;
            float v = (latl[e * 132 + li] - mu) * rstd * ln_g[li] + ln_b[li];
            lnscal_ws[(size_t)eg * 192 + li] = f2b(v);
        }
    }
}

// ============================================================================
// K2: A-MLP (192->128->128->128) + B-MLP (256->128->128->128) + O-projections
//     + latent scatter.  32 edges / 256-thread block.
// ============================================================================
__device__ __forceinline__ void mlp_accum(const us_t* xrow, const float* W, int K,
                                          int nbase, float4 acc[4])
{
    for (int k = 0; k < K; k += 4) {
        ushort4 xv = *(const ushort4*)&xrow[k];
        float aa[4] = {b2f(xv.x), b2f(xv.y), b2f(xv.z), b2f(xv.w)};
        #pragma unroll
        for (int kk = 0; kk < 4; ++kk) {
            const float* wr = W + (size_t)(k + kk) * 128 + nbase;
            float a = aa[kk];
            #pragma unroll
            for (int j = 0; j < 4; ++j) {
                float4 wv = *(const float4*)(wr + 32 * j);
                acc[j].x += a * wv.x; acc[j].y += a * wv.y;
                acc[j].z += a * wv.z; acc[j].w += a * wv.w;
            }
        }
    }
}

__device__ __forceinline__ void store_act(const float4 acc[4], us_t* dst, int nbase, bool do_silu)
{
    #pragma unroll
    for (int j = 0; j < 4; ++j) {
        float4 v = acc[j];
        if (do_silu) {
            v.x *= sigm(v.x); v.y *= sigm(v.y); v.z *= sigm(v.z); v.w *= sigm(v.w);
        }
        ushort4 s; s.x = f2b(v.x); s.y = f2b(v.y); s.z = f2b(v.z); s.w = f2b(v.w);
        *(ushort4*)&dst[nbase + 32 * j] = s;
    }
}

__global__ __launch_bounds__(256) void k2_kernel(
    const float* __restrict__ latents, const float* __restrict__ cutoff,
    const float* __restrict__ one_hot,
    const float* __restrict__ A1, const float* __restrict__ A1b,
    const float* __restrict__ A2, const float* __restrict__ A2b,
    const float* __restrict__ A3, const float* __restrict__ A3b,
    const float* __restrict__ B1, const float* __restrict__ B1b,
    const float* __restrict__ B2, const float* __restrict__ B2b,
    const float* __restrict__ B3, const float* __restrict__ B3b,
    const float* __restrict__ O0, const float* __restrict__ O1, const float* __restrict__ O2,
    const int* __restrict__ active_edges,
    const us_t* __restrict__ lnscal_ws, us_t* __restrict__ ohw_ws,
    float* __restrict__ out_lat)
{
    __shared__ __align__(16) char smem[43008];
    us_t* x_lds = (us_t*)(smem);           // [32][200] (192 used)
    float* h3s  = (float*)(smem);          // [32][132] alias (x dead after A1)
    us_t* h_a   = (us_t*)(smem + 16896);   // [32][136] (128 used)
    us_t* h_b   = (us_t*)(smem + 25600);   // [32][136]
    us_t* ohl   = (us_t*)(smem + 34304);   // [32][136]

    const int t  = threadIdx.x;
    const int e0 = blockIdx.x * 32;

    for (int idx = t; idx < 32 * 192; idx += 256) {
        int ee = idx / 192, i = idx - ee * 192;
        x_lds[ee * 200 + i] = lnscal_ws[(size_t)(e0 + ee) * 192 + i];
    }
    for (int idx = t; idx < 32 * 128; idx += 256) {
        int ee = idx >> 7, i = idx & 127;
        ohl[ee * 136 + i] = f2b(one_hot[(size_t)(e0 + ee) * 128 + i]);
    }
    __syncthreads();

    const int e = t & 31, q = t >> 5;
    const int eg = e0 + e;
    float4 acc[4];

    // A1 (K=192) + silu
    #pragma unroll
    for (int j = 0; j < 4; ++j) acc[j] = *(const float4*)&A1b[q * 4 + 32 * j];
    mlp_accum(&x_lds[e * 200], A1, 192, q * 4, acc);
    store_act(acc, &h_a[e * 136], q * 4, true);
    __syncthreads();
    // A2 + silu
    #pragma unroll
    for (int j = 0; j < 4; ++j) acc[j] = *(const float4*)&A2b[q * 4 + 32 * j];
    mlp_accum(&h_a[e * 136], A2, 128, q * 4, acc);
    store_act(acc, &h_b[e * 136], q * 4, true);
    __syncthreads();
    // A3 (no act)
    #pragma unroll
    for (int j = 0; j < 4; ++j) acc[j] = *(const float4*)&A3b[q * 4 + 32 * j];
    mlp_accum(&h_b[e * 136], A3, 128, q * 4, acc);
    store_act(acc, &h_a[e * 136], q * 4, false);
    __syncthreads();
    // B1: concat(h, one_hot) (K=256) + silu
    #pragma unroll
    for (int j = 0; j < 4; ++j) acc[j] = *(const float4*)&B1b[q * 4 + 32 * j];
    mlp_accum(&h_a[e * 136], B1, 128, q * 4, acc);
    mlp_accum(&ohl[e * 136], B1 + 128 * 128, 128, q * 4, acc);
    store_act(acc, &h_b[e * 136], q * 4, true);
    __syncthreads();
    // B2 + silu
    #pragma unroll
    for (int j = 0; j < 4; ++j) acc[j] = *(const float4*)&B2b[q * 4 + 32 * j];
    mlp_accum(&h_b[e * 136], B2, 128, q * 4, acc);
    store_act(acc, &h_a[e * 136], q * 4, true);
    __syncthreads();
    // B3 (no act) -> f32 staging
    #pragma unroll
    for (int j = 0; j < 4; ++j) acc[j] = *(const float4*)&B3b[q * 4 + 32 * j];
    mlp_accum(&h_a[e * 136], B3, 128, q * 4, acc);
    #pragma unroll
    for (int j = 0; j < 4; ++j) *(float4*)&h3s[e * 132 + q * 4 + 32 * j] = acc[j];
    __syncthreads();

    // O-projections: oh0 (64), oh1 (32), oh2 (16); row-major (N,128) weights
    {
        const us_t* xr = &ohl[e * 136];
        float acc0[8], acc1[4], acc2[2];
        #pragma unroll
        for (int j = 0; j < 8; ++j) acc0[j] = 0.f;
        #pragma unroll
        for (int j = 0; j < 4; ++j) acc1[j] = 0.f;
        #pragma unroll
        for (int j = 0; j < 2; ++j) acc2[j] = 0.f;
        for (int k = 0; k < 128; k += 4) {
            ushort4 xv = *(const ushort4*)&xr[k];
            float a0 = b2f(xv.x), a1 = b2f(xv.y), a2 = b2f(xv.z), a3 = b2f(xv.w);
            #pragma unroll
            for (int j = 0; j < 8; ++j) {
                float4 wv = *(const float4*)(O0 + (size_t)(q * 8 + j) * 128 + k);
                acc0[j] += a0 * wv.x + a1 * wv.y + a2 * wv.z + a3 * wv.w;
            }
            #pragma unroll
            for (int j = 0; j < 4; ++j) {
                float4 wv = *(const float4*)(O1 + (size_t)(q * 4 + j) * 128 + k);
                acc1[j] += a0 * wv.x + a1 * wv.y + a2 * wv.z + a3 * wv.w;
            }
            #pragma unroll
            for (int j = 0; j < 2; ++j) {
                float4 wv = *(const float4*)(O2 + (size_t)(q * 2 + j) * 128 + k);
                acc2[j] += a0 * wv.x + a1 * wv.y + a2 * wv.z + a3 * wv.w;
            }
        }
        #pragma unroll
        for (int j = 0; j < 8; ++j) ohw_ws[(size_t)eg * 112 + q * 8 + j] = f2b(acc0[j]);
        #pragma unroll
        for (int j = 0; j < 4; ++j) ohw_ws[(size_t)eg * 112 + 64 + q * 4 + j] = f2b(acc1[j]);
        #pragma unroll
        for (int j = 0; j < 2; ++j) ohw_ws[(size_t)eg * 112 + 96 + q * 2 + j] = f2b(acc2[j]);
    }

    // Latent scatter: out_lat[ae] = c_new*cutoff[ae]*h + c_old*lat[ae]
    for (int idx = t; idx < 1024; idx += 256) {
        int ee = idx >> 5, c4 = (idx & 31) * 4;
        int aeg = e0 + ee;
        int ae  = active_edges[aeg];
        float cut = cutoff[ae];
        float4 lv = *(const float4*)&latents[(size_t)ae * 128 + c4];
        float4 hv = *(const float4*)&h3s[ee * 132 + c4];
        float4 ov;
        ov.x = C_NEW * cut * hv.x + C_OLD * lv.x;
        ov.y = C_NEW * cut * hv.y + C_OLD * lv.y;
        ov.z = C_NEW * cut * hv.z + C_OLD * lv.z;
        ov.w = C_NEW * cut * hv.w + C_OLD * lv.w;
        *(float4*)&out_lat[(size_t)ae * 128 + c4] = ov;
    }
}

// ============================================================================
// K3: edge_out = (c_old*ef + c_new*new_edge) * (1 + s*oh_factor)
// ============================================================================
__global__ __launch_bounds__(256) void kfin_kernel(
    const float* __restrict__ edge_features, const float* __restrict__ ne_ws,
    const us_t* __restrict__ ohw_ws, float* __restrict__ out_edge)
{
    int idx = blockIdx.x * 256 + threadIdx.x;
    if (idx >= E_ACT * DIR) return;
    int e = idx / DIR;
    int c = idx - e * DIR;
    float base = C_OLD * edge_features[idx] + C_NEW * ne_ws[idx];
    int o;
    if (c < 64)       o = c;
    else if (c < 160) o = 64 + (c - 64) / 3;
    else              o = 96 + (c - 160) / 5;
    float ohv = b2f(ohw_ws[(size_t)e * 112 + o]);
    out_edge[idx] = base * (1.f + S_OH * ohv);
}

// ============================================================================
extern "C" void kernel_launch(void* const* d_in, const int* in_sizes, int n_in,
                              void* d_out, int out_size, void* d_ws, size_t ws_size,
                              hipStream_t stream)
{
    const float* latents  = (const float*)d_in[0];
    const float* node_f   = (const float*)d_in[1];
    const float* edge_f   = (const float*)d_in[2];
    const float* cutoff   = (const float*)d_in[3];
    const float* one_hot  = (const float*)d_in[4];
    const float* wD1      = (const float*)d_in[5];
    const float* wD2      = (const float*)d_in[6];
    const float* W0       = (const float*)d_in[7];
    const float* W1r      = (const float*)d_in[8];
    const float* W1i      = (const float*)d_in[9];
    const float* W2r      = (const float*)d_in[10];
    const float* W2i      = (const float*)d_in[11];
    const float* Gw       = (const float*)d_in[12];
    const float* Gb       = (const float*)d_in[13];
    const float* P0w      = (const float*)d_in[14];
    const float* P0b      = (const float*)d_in[15];
    const float* P1w      = (const float*)d_in[16];
    const float* P2w      = (const float*)d_in[17];
    const float* Ew       = (const float*)d_in[18];
    const float* Eb       = (const float*)d_in[19];
    const float* ln_g     = (const float*)d_in[20];
    const float* ln_b     = (const float*)d_in[21];
    const float* A1       = (const float*)d_in[22];
    const float* A1b      = (const float*)d_in[23];
    const float* A2       = (const float*)d_in[24];
    const float* A2b      = (const float*)d_in[25];
    const float* A3       = (const float*)d_in[26];
    const float* A3b      = (const float*)d_in[27];
    const float* B1       = (const float*)d_in[28];
    const float* B1b      = (const float*)d_in[29];
    const float* B2       = (const float*)d_in[30];
    const float* B2b      = (const float*)d_in[31];
    const float* B3       = (const float*)d_in[32];
    const float* B3b      = (const float*)d_in[33];
    const float* O0       = (const float*)d_in[34];
    const float* O1       = (const float*)d_in[35];
    const float* O2       = (const float*)d_in[36];
    const int* edge_index = (const int*)d_in[37];
    const int* act_e      = (const int*)d_in[38];

    float* out_edge = (float*)d_out;                      // E_ACT*240
    float* out_lat  = out_edge + (size_t)E_ACT * DIR;     // E_TOT*128

    float* ne_ws     = (float*)d_ws;                              // E_ACT*240 f32
    us_t*  lnscal_ws = (us_t*)(ne_ws + (size_t)E_ACT * DIR);      // E_ACT*192 bf16
    us_t*  ohw_ws    = lnscal_ws + (size_t)E_ACT * 192;           // E_ACT*112 bf16

    // latents passthrough copy (active rows overwritten by k2's scatter)
    hipMemcpyAsync(out_lat, latents, (size_t)E_TOT * 128 * sizeof(float),
                   hipMemcpyDeviceToDevice, stream);

    k1_kernel<<<dim3(E_ACT / 16), dim3(256), 0, stream>>>(
        latents, node_f, edge_f, wD1, wD2, W0, W1r, W1i, W2r, W2i,
        Gw, Gb, P0w, P0b, P1w, P2w, Ew, Eb, ln_g, ln_b,
        edge_index, act_e, ne_ws, lnscal_ws);

    k2_kernel<<<dim3(E_ACT / 32), dim3(256), 0, stream>>>(
        latents, cutoff, one_hot, A1, A1b, A2, A2b, A3, A3b,
        B1, B1b, B2, B2b, B3, B3b, O0, O1, O2, act_e,
        lnscal_ws, ohw_ws, out_lat);

    kfin_kernel<<<dim3((E_ACT * DIR) / 256), dim3(256), 0, stream>>>(
        edge_f, ne_ws, ohw_ws, out_edge);
}

// Round 2
// 1687.452 us; speedup vs baseline: 6.3432x; 6.3432x over previous
//
#include <hip/hip_runtime.h>

typedef unsigned short us_t;
typedef short bf16x8 __attribute__((ext_vector_type(8)));
typedef float f32x4 __attribute__((ext_vector_type(4)));

#define E_ACT 200000
#define E_TOT 250000
#define DIR   240
#define C_OLD 0.8944271909999159f
#define C_NEW 0.4472135954999579f
#define S_OH  0.08838834764831845f   // 1/sqrt(128)

// ---- transposed bf16 weight arena offsets (elements) ----
#define WO_W0   0         // [160][352]
#define WO_W1P  56320     // [48][288]
#define WO_W1M  70144     // [48][288]
#define WO_W2P  83968     // [16][96]
#define WO_W2M  85504     // [16][96]
#define WO_GW   87040     // [224][128]
#define WO_EW   115712    // [112][128]
#define WO_A1   130048    // [128][192]
#define WO_A2   154624    // [128][128]
#define WO_A3   171008    // [128][128]
#define WO_B1   187392    // [128][256]
#define WO_B2   220160    // [128][128]
#define WO_B3   236544    // [128][128]
#define WO_O0   252928    // [64][128]
#define WO_O1   261120    // [32][128]
#define WO_O2   265216    // [16][128]
#define W_TOTAL 267264

__device__ __forceinline__ float b2f(us_t u) { return __uint_as_float(((unsigned)u) << 16); }
__device__ __forceinline__ us_t f2b(float f) {
    unsigned x = __float_as_uint(f);
    return (us_t)((x + 0x7fffu + ((x >> 16) & 1u)) >> 16);   // RNE
}
__device__ __forceinline__ float sigm(float x) { return 1.0f / (1.0f + __expf(-x)); }

#define MFMA(a,b,c) __builtin_amdgcn_mfma_f32_16x16x32_bf16((a),(b),(c),0,0,0)

// ============================================================================
// prep: build transposed/padded bf16 weights in workspace
// ============================================================================
__global__ __launch_bounds__(256) void prep_kernel(
    const float* __restrict__ W0, const float* __restrict__ W1r, const float* __restrict__ W1i,
    const float* __restrict__ W2r, const float* __restrict__ W2i,
    const float* __restrict__ Gw, const float* __restrict__ Ew,
    const float* __restrict__ A1, const float* __restrict__ A2, const float* __restrict__ A3,
    const float* __restrict__ B1, const float* __restrict__ B2, const float* __restrict__ B3,
    const float* __restrict__ O0, const float* __restrict__ O1, const float* __restrict__ O2,
    us_t* __restrict__ wb)
{
    int idx = blockIdx.x * 256 + threadIdx.x;
    if (idx >= W_TOTAL) return;
    float v;
    if (idx < WO_W1P) {                        // W0T [160][352], pad k 336->352
        int r = idx, n = r / 352, k = r % 352;
        v = (k < 336) ? W0[n * 336 + k] : 0.f;
    } else if (idx < WO_W1M) {                 // [W1r | -W1i]  [48][288]
        int r = idx - WO_W1P, n = r / 288, k = r % 288;
        v = (k < 144) ? W1r[n * 144 + k] : -W1i[n * 144 + (k - 144)];
    } else if (idx < WO_W2P) {                 // [W1i | W1r]
        int r = idx - WO_W1M, n = r / 288, k = r % 288;
        v = (k < 144) ? W1i[n * 144 + k] : W1r[n * 144 + (k - 144)];
    } else if (idx < WO_W2M) {                 // [W2r | -W2i]  [16][96]
        int r = idx - WO_W2P, n = r / 96, k = r % 96;
        v = (k < 48) ? W2r[n * 48 + k] : -W2i[n * 48 + (k - 48)];
    } else if (idx < WO_GW) {                  // [W2i | W2r]
        int r = idx - WO_W2M, n = r / 96, k = r % 96;
        v = (k < 48) ? W2i[n * 48 + k] : W2r[n * 48 + (k - 48)];
    } else if (idx < WO_EW) {                  // GwT [224][128]
        int r = idx - WO_GW, n = r / 128, k = r % 128;
        v = Gw[k * 224 + n];
    } else if (idx < WO_A1) {                  // EwT [112][128]
        int r = idx - WO_EW, n = r / 128, k = r % 128;
        v = Ew[k * 112 + n];
    } else if (idx < WO_A2) {                  // A1T [128][192]
        int r = idx - WO_A1, n = r / 192, k = r % 192;
        v = A1[k * 128 + n];
    } else if (idx < WO_A3) {                  // A2T [128][128]
        int r = idx - WO_A2, n = r / 128, k = r % 128;
        v = A2[k * 128 + n];
    } else if (idx < WO_B1) {                  // A3T
        int r = idx - WO_A3, n = r / 128, k = r % 128;
        v = A3[k * 128 + n];
    } else if (idx < WO_B2) {                  // B1T [128][256]
        int r = idx - WO_B1, n = r / 256, k = r % 256;
        v = B1[k * 128 + n];
    } else if (idx < WO_B3) {                  // B2T
        int r = idx - WO_B2, n = r / 128, k = r % 128;
        v = B2[k * 128 + n];
    } else if (idx < WO_O0) {                  // B3T
        int r = idx - WO_B3, n = r / 128, k = r % 128;
        v = B3[k * 128 + n];
    } else if (idx < WO_O1) {                  // O0 [64][128] already N-major
        v = O0[idx - WO_O0];
    } else if (idx < WO_O2) {
        v = O1[idx - WO_O1];
    } else {
        v = O2[idx - WO_O2];
    }
    wb[idx] = f2b(v);
}

// ---- per-wave MFMA tile helpers (A: LDS bf16 rows, B: global bf16 [N][kp]) ----
template<int KS>
__device__ __forceinline__ void gemm2(
    const us_t* __restrict__ act, int as,
    const us_t* __restrict__ wgt, int kp, const float* __restrict__ bias,
    int nt0, int nt1, us_t* __restrict__ out, int os, int lane)
{
    const int r = lane & 15, g = lane >> 4;
    f32x4 acc0 = {0.f,0.f,0.f,0.f}, acc1 = {0.f,0.f,0.f,0.f};
    const us_t* ap  = act + r * as + g * 8;
    const us_t* wp0 = wgt + (size_t)(nt0 * 16 + r) * kp + g * 8;
    const us_t* wp1 = wgt + (size_t)(nt1 * 16 + r) * kp + g * 8;
    #pragma unroll
    for (int ks = 0; ks < KS; ++ks) {
        bf16x8 a  = *(const bf16x8*)(ap  + ks * 32);
        bf16x8 b0 = *(const bf16x8*)(wp0 + ks * 32);
        bf16x8 b1 = *(const bf16x8*)(wp1 + ks * 32);
        acc0 = MFMA(a, b0, acc0);
        acc1 = MFMA(a, b1, acc1);
    }
    float bi0 = bias ? bias[nt0 * 16 + r] : 0.f;
    float bi1 = bias ? bias[nt1 * 16 + r] : 0.f;
    #pragma unroll
    for (int i = 0; i < 4; ++i) {
        int e = g * 4 + i;
        out[e * os + nt0 * 16 + r] = f2b(acc0[i] + bi0);
        out[e * os + nt1 * 16 + r] = f2b(acc1[i] + bi1);
    }
}

template<int KS>
__device__ __forceinline__ void gemm1(
    const us_t* __restrict__ act, int as,
    const us_t* __restrict__ wgt, int kp, const float* __restrict__ bias,
    int nt, us_t* __restrict__ out, int os, int lane)
{
    const int r = lane & 15, g = lane >> 4;
    f32x4 acc = {0.f,0.f,0.f,0.f};
    const us_t* ap = act + r * as + g * 8;
    const us_t* wp = wgt + (size_t)(nt * 16 + r) * kp + g * 8;
    #pragma unroll
    for (int ks = 0; ks < KS; ++ks) {
        bf16x8 a = *(const bf16x8*)(ap + ks * 32);
        bf16x8 b = *(const bf16x8*)(wp + ks * 32);
        acc = MFMA(a, b, acc);
    }
    float bi = bias ? bias[nt * 16 + r] : 0.f;
    #pragma unroll
    for (int i = 0; i < 4; ++i) {
        int e = g * 4 + i;
        out[e * os + nt * 16 + r] = f2b(acc[i] + bi);
    }
}

// ============================================================================
// K1: gather + rotations + MFMA stage-1 GEMMs + y-build/D^T + P0/P1/P2 + LN
//     16 edges / 256-thread block (4 waves).
// ============================================================================
__global__ __launch_bounds__(256) void k1_kernel(
    const float* __restrict__ latents,
    const float* __restrict__ node_features,
    const float* __restrict__ edge_features,
    const float* __restrict__ wD1,
    const float* __restrict__ wD2,
    const float* __restrict__ Gb,  const float* __restrict__ Eb,
    const float* __restrict__ P0w, const float* __restrict__ P0b,
    const float* __restrict__ P1w, const float* __restrict__ P2w,
    const float* __restrict__ ln_g, const float* __restrict__ ln_b,
    const int* __restrict__ edge_index, const int* __restrict__ active_edges,
    const us_t* __restrict__ wbase,
    us_t* __restrict__ ne_ws, us_t* __restrict__ lnscal_ws)
{
    __shared__ __align__(16) char smem[54528];
    us_t* in0s  = (us_t*)(smem);            // [16][360] k used 0..352 (W0)
    us_t* cact1 = (us_t*)(smem + 11520);    // [16][296] [ip1|im1] K=288
    us_t* cact2 = (us_t*)(smem + 20992);    // [16][104] [r24|r20] K=96
    us_t* latb  = (us_t*)(smem + 24320);    // [16][136] bf16 latents K=128
    float* D1l  = (float*)(smem + 28672);   // [16][12]
    float* D2l  = (float*)(smem + 29440);   // [16][28]
    int*   aes  = (int*)(smem + 31232);     // [16]
    // union: phase-A staging, then MFMA raw outputs
    us_t* stg   = (us_t*)(smem + 31296);    // [3][16][242]
    us_t* om0r  = (us_t*)(smem + 31296);    // [16][168] raw o_m0 (160)
    us_t* cp1r  = (us_t*)(smem + 36672);    // [16][56]  raw op1 (48)
    us_t* cn1r  = (us_t*)(smem + 38464);    // [16][56]  raw on1
    us_t* cp2r  = (us_t*)(smem + 40256);    // [16][24]  raw op2 (16)
    us_t* cn2r  = (us_t*)(smem + 41024);    // [16][24]  raw on2
    us_t* gl    = (us_t*)(smem + 41792);    // [16][232] g (=lat@Gw+Gb, 224)
    us_t* wl    = (us_t*)(smem + 49216);    // [16][120] w (=lat@Ew+Eb, 112)
    // union (phase C): z buffers alias act region
    float* z1l  = (float*)(smem);           // [16][100] (96 used)
    float* z2l  = (float*)(smem + 6400);    // [16][84]  (80 used)
    float* z0l  = (float*)(smem + 11776);   // [16][68]  (64 used)

    const int t  = threadIdx.x;
    const int e0 = blockIdx.x * 16;

    // ---------------- Phase A: loads ----------------
    {
        const int e = t >> 4, l = t & 15;
        const int eg = e0 + e;
        const int ae = active_edges[eg];
        const int ec = edge_index[ae];
        const int en = edge_index[E_TOT + ae];
        if (l == 0) aes[e] = ae;
        const float* nfc = node_features + (size_t)ec * DIR;
        const float* nfn = node_features + (size_t)en * DIR;
        const float* efp = edge_features + (size_t)eg * DIR;
        us_t* s_nfc = stg + (0 * 16 + e) * 242;
        us_t* s_ef  = stg + (1 * 16 + e) * 242;
        us_t* s_nfn = stg + (2 * 16 + e) * 242;
        for (int i = l; i < DIR; i += 16) {
            s_nfc[i] = f2b(nfc[i]);
            s_ef[i]  = f2b(efp[i]);
            s_nfn[i] = f2b(nfn[i]);
        }
        const float* lp = latents + (size_t)ae * 128;
        for (int i = l; i < 128; i += 16) latb[e * 136 + i] = f2b(lp[i]);
        if (l < 9) D1l[e * 12 + l] = wD1[(size_t)eg * 9 + l];
        D2l[e * 28 + l] = wD2[(size_t)eg * 25 + l];
        if (l < 9) D2l[e * 28 + 16 + l] = wD2[(size_t)eg * 25 + 16 + l];
    }
    __syncthreads();

    // ---------------- Phase A2: build activations ----------------
    {
        const int e = t >> 4, l = t & 15;
        const us_t* s_nfc = stg + (0 * 16 + e) * 242;
        const us_t* s_ef  = stg + (1 * 16 + e) * 242;
        const us_t* s_nfn = stg + (2 * 16 + e) * 242;
        us_t* in0 = in0s + e * 360;
        us_t* c1  = cact1 + e * 296;
        us_t* c2  = cact2 + e * 104;
        for (int i = l; i < 64; i += 16) {
            in0[i]       = s_nfc[i];
            in0[64 + i]  = s_ef[i];
            in0[128 + i] = s_nfn[i];
        }
        in0[336 + l] = 0;   // zero K-pad 336..352
        const float* D1e = D1l + e * 12;
        for (int u = l; u < 96; u += 16) {
            const us_t* src; int base;
            if (u < 32)      { src = s_nfc; base = 64 + u * 3; }
            else if (u < 64) { src = s_ef;  base = 64 + (u - 32) * 3; }
            else             { src = s_nfn; base = 64 + (u - 64) * 3; }
            float x0 = b2f(src[base]), x1 = b2f(src[base + 1]), x2 = b2f(src[base + 2]);
            float r0 = D1e[0] * x0 + D1e[1] * x1 + D1e[2] * x2;
            float r1 = D1e[3] * x0 + D1e[4] * x1 + D1e[5] * x2;
            float r2 = D1e[6] * x0 + D1e[7] * x1 + D1e[8] * x2;
            c1[144 + u]  = f2b(r0);   // im1 part 1 (r1 i=0)
            in0[192 + u] = f2b(r1);
            c1[u]        = f2b(r2);   // ip1 part 1 (r1 i=2)
        }
        const float* D2e = D2l + e * 28;
        for (int u = l; u < 48; u += 16) {
            const us_t* src; int base;
            if (u < 16)      { src = s_nfc; base = 160 + u * 5; }
            else if (u < 32) { src = s_ef;  base = 160 + (u - 16) * 5; }
            else             { src = s_nfn; base = 160 + (u - 32) * 5; }
            float x0 = b2f(src[base]),     x1 = b2f(src[base + 1]), x2 = b2f(src[base + 2]);
            float x3 = b2f(src[base + 3]), x4 = b2f(src[base + 4]);
            float r[5];
            #pragma unroll
            for (int i = 0; i < 5; ++i)
                r[i] = D2e[i * 5 + 0] * x0 + D2e[i * 5 + 1] * x1 + D2e[i * 5 + 2] * x2
                     + D2e[i * 5 + 3] * x3 + D2e[i * 5 + 4] * x4;
            c2[48 + u]   = f2b(r[0]);  // r20
            c1[240 + u]  = f2b(r[1]);  // im1 part 2 (r2 i=1)
            in0[288 + u] = f2b(r[2]);
            c1[96 + u]   = f2b(r[3]);  // ip1 part 2 (r2 i=3)
            c2[u]        = f2b(r[4]);  // r24
        }
    }
    __syncthreads();

    // ---------------- Phase B: MFMA GEMMs (per-wave static tile lists) ----------------
    {
        const int lane = t & 63, w = t >> 6;
        if (w == 0) {
            gemm2<11>(in0s, 360, wbase + WO_W0, 352, nullptr, 0, 1, om0r, 168, lane);
            gemm2<11>(in0s, 360, wbase + WO_W0, 352, nullptr, 2, 3, om0r, 168, lane);
            gemm2<11>(in0s, 360, wbase + WO_W0, 352, nullptr, 4, 5, om0r, 168, lane);
        } else if (w == 1) {
            gemm2<11>(in0s, 360, wbase + WO_W0, 352, nullptr, 6, 7, om0r, 168, lane);
            gemm2<11>(in0s, 360, wbase + WO_W0, 352, nullptr, 8, 9, om0r, 168, lane);
            gemm1<3>(cact2, 104, wbase + WO_W2P, 96, nullptr, 0, cp2r, 24, lane);
            gemm1<3>(cact2, 104, wbase + WO_W2M, 96, nullptr, 0, cn2r, 24, lane);
            gemm2<4>(latb, 136, wbase + WO_EW, 128, Eb, 0, 1, wl, 120, lane);
        } else if (w == 2) {
            gemm2<9>(cact1, 296, wbase + WO_W1P, 288, nullptr, 0, 1, cp1r, 56, lane);
            gemm1<9>(cact1, 296, wbase + WO_W1P, 288, nullptr, 2, cp1r, 56, lane);
            gemm2<9>(cact1, 296, wbase + WO_W1M, 288, nullptr, 0, 1, cn1r, 56, lane);
            gemm1<9>(cact1, 296, wbase + WO_W1M, 288, nullptr, 2, cn1r, 56, lane);
            gemm2<4>(latb, 136, wbase + WO_EW, 128, Eb, 2, 3, wl, 120, lane);
            gemm1<4>(latb, 136, wbase + WO_EW, 128, Eb, 4, wl, 120, lane);
        } else {
            for (int p = 0; p < 7; ++p)
                gemm2<4>(latb, 136, wbase + WO_GW, 128, Gb, 2 * p, 2 * p + 1, gl, 232, lane);
            gemm2<4>(latb, 136, wbase + WO_EW, 128, Eb, 5, 6, wl, 120, lane);
        }
    }
    __syncthreads();

    // ---------------- Phase C1: gate + y-build + D^T rotations + silu ----------------
    {
        const int e = t >> 4, l = t & 15;
        const float* D1e = D1l + e * 12;
        const float* D2e = D2l + e * 28;
        #pragma unroll
        for (int uu = 0; uu < 2; ++uu) {
            int u = l + uu * 16;
            float g1 = b2f(gl[e * 232 + 160 + u]);
            float j0 = b2f(cn1r[e * 56 + u]) * g1;
            float j1 = b2f(om0r[e * 168 + 112 + u]) * b2f(gl[e * 232 + 112 + u]);
            float j2 = b2f(cp1r[e * 56 + u]) * g1;
            float gate = sigm(b2f(om0r[e * 168 + 64 + u]) * b2f(gl[e * 232 + 64 + u]));
            #pragma unroll
            for (int i = 0; i < 3; ++i) {
                float yr = D1e[0 * 3 + i] * j0 + D1e[1 * 3 + i] * j1 + D1e[2 * 3 + i] * j2;
                z1l[e * 100 + u * 3 + i] = yr * gate;
            }
        }
        {
            int u = l;
            float g2 = b2f(gl[e * 232 + 208 + u]);
            float g1b = b2f(gl[e * 232 + 192 + u]);
            float j0 = b2f(cn2r[e * 24 + u]) * g2;
            float j1 = b2f(cn1r[e * 56 + 32 + u]) * g1b;
            float j2 = b2f(om0r[e * 168 + 144 + u]) * b2f(gl[e * 232 + 144 + u]);
            float j3 = b2f(cp1r[e * 56 + 32 + u]) * g1b;
            float j4 = b2f(cp2r[e * 24 + u]) * g2;
            float gate = sigm(b2f(om0r[e * 168 + 96 + u]) * b2f(gl[e * 232 + 96 + u]));
            #pragma unroll
            for (int i = 0; i < 5; ++i) {
                float yr = D2e[0 * 5 + i] * j0 + D2e[1 * 5 + i] * j1 + D2e[2 * 5 + i] * j2
                         + D2e[3 * 5 + i] * j3 + D2e[4 * 5 + i] * j4;
                z2l[e * 84 + u * 5 + i] = yr * gate;
            }
        }
        #pragma unroll
        for (int ii = 0; ii < 4; ++ii) {
            int c = l + 16 * ii;
            float v = b2f(om0r[e * 168 + c]) * b2f(gl[e * 232 + c]);
            z0l[e * 68 + c] = v * sigm(v);
        }
    }
    __syncthreads();

    // ---------------- Phase C2: P0/P1/P2 + w-scale + scalars + LayerNorm ----------------
    {
        const int e = t >> 4, l = t & 15;
        const int eg = e0 + e;
        #pragma unroll
        for (int j = 0; j < 4; ++j) {
            int n = l + 16 * j;
            float acc = 0.f;
            for (int k = 0; k < 64; k += 4) {
                float4 zv = *(const float4*)&z0l[e * 68 + k];
                float4 pw = *(const float4*)&P0w[n * 64 + k];
                acc += zv.x * pw.x + zv.y * pw.y + zv.z * pw.z + zv.w * pw.w;
            }
            float z0p = acc * 0.125f + P0b[n];
            lnscal_ws[(size_t)eg * 192 + 128 + n] = f2b(z0p);
            ne_ws[(size_t)eg * 240 + n] = f2b(z0p * b2f(wl[e * 120 + n]));
        }
        #pragma unroll
        for (int uu = 0; uu < 2; ++uu) {
            int u = l + uu * 16;
            float wv = b2f(wl[e * 120 + 64 + u]);
            #pragma unroll
            for (int m = 0; m < 3; ++m) {
                float acc = 0.f;
                for (int v = 0; v < 32; ++v)
                    acc += P1w[u * 32 + v] * z1l[e * 100 + v * 3 + m];
                ne_ws[(size_t)eg * 240 + 64 + u * 3 + m] = f2b(acc * 0.17677669529663687f * wv);
            }
        }
        {
            int u = l;
            float wv = b2f(wl[e * 120 + 96 + u]);
            #pragma unroll
            for (int m = 0; m < 5; ++m) {
                float acc = 0.f;
                for (int v = 0; v < 16; ++v)
                    acc += P2w[u * 16 + v] * z2l[e * 84 + v * 5 + m];
                ne_ws[(size_t)eg * 240 + 160 + u * 5 + m] = f2b(acc * 0.25f * wv);
            }
        }
        // LayerNorm from global latents (f32)
        const int ae = aes[e];
        const float* lp = latents + (size_t)ae * 128 + l * 8;
        float4 va = *(const float4*)lp;
        float4 vb = *(const float4*)(lp + 4);
        float xs[8] = {va.x, va.y, va.z, va.w, vb.x, vb.y, vb.z, vb.w};
        float s1 = 0.f, s2 = 0.f;
        #pragma unroll
        for (int i = 0; i < 8; ++i) { s1 += xs[i]; s2 += xs[i] * xs[i]; }
        #pragma unroll
        for (int off = 1; off < 16; off <<= 1) {
            s1 += __shfl_xor(s1, off, 16);
            s2 += __shfl_xor(s2, off, 16);
        }
        float mu  = s1 * (1.f / 128.f);
        float var = s2 * (1.f / 128.f) - mu * mu;
        float rstd = rsqrtf(var + 1e-5f);
        #pragma unroll
        for (int i = 0; i < 8; ++i) {
            int li = l * 8 + i;
            float v = (xs[i] - mu) * rstd * ln_g[li] + ln_b[li];
            lnscal_ws[(size_t)eg * 192 + li] = f2b(v);
        }
    }
}

// ============================================================================
// K2: MFMA MLP chain + O-projections + latent scatter. 32 edges / 4 waves.
// ============================================================================
template<int KS, bool SILU>
__device__ __forceinline__ void mlayer(
    const us_t* __restrict__ actA, const us_t* __restrict__ actB, int split, int as,
    const us_t* __restrict__ wgt, int kp, const float* __restrict__ bias,
    us_t* __restrict__ out, int os, int lane, int w)
{
    const int r = lane & 15, g = lane >> 4;
    const int n0 = 2 * w * 16, n1 = n0 + 16;
    f32x4 a00 = {0.f,0.f,0.f,0.f}, a01 = a00, a10 = a00, a11 = a00;
    const us_t* wp0 = wgt + (size_t)(n0 + r) * kp + g * 8;
    const us_t* wp1 = wgt + (size_t)(n1 + r) * kp + g * 8;
    #pragma unroll
    for (int ks = 0; ks < KS; ++ks) {
        const us_t* ab = (ks < split) ? (actA + ks * 32) : (actB + (ks - split) * 32);
        bf16x8 f0 = *(const bf16x8*)(ab + r * as + g * 8);
        bf16x8 f1 = *(const bf16x8*)(ab + (16 + r) * as + g * 8);
        bf16x8 b0 = *(const bf16x8*)(wp0 + ks * 32);
        bf16x8 b1 = *(const bf16x8*)(wp1 + ks * 32);
        a00 = MFMA(f0, b0, a00); a01 = MFMA(f0, b1, a01);
        a10 = MFMA(f1, b0, a10); a11 = MFMA(f1, b1, a11);
    }
    float bi0 = bias[n0 + r], bi1 = bias[n1 + r];
    #pragma unroll
    for (int i = 0; i < 4; ++i) {
        int eA = g * 4 + i, eB = 16 + g * 4 + i;
        float v;
        v = a00[i] + bi0; if (SILU) v *= sigm(v); out[eA * os + n0 + r] = f2b(v);
        v = a01[i] + bi1; if (SILU) v *= sigm(v); out[eA * os + n1 + r] = f2b(v);
        v = a10[i] + bi0; if (SILU) v *= sigm(v); out[eB * os + n0 + r] = f2b(v);
        v = a11[i] + bi1; if (SILU) v *= sigm(v); out[eB * os + n1 + r] = f2b(v);
    }
}

__global__ __launch_bounds__(256) void k2_kernel(
    const float* __restrict__ latents, const float* __restrict__ cutoff,
    const float* __restrict__ one_hot,
    const float* __restrict__ A1b, const float* __restrict__ A2b, const float* __restrict__ A3b,
    const float* __restrict__ B1b, const float* __restrict__ B2b, const float* __restrict__ B3b,
    const int* __restrict__ active_edges,
    const us_t* __restrict__ wbase,
    const us_t* __restrict__ lnscal_ws, us_t* __restrict__ ohw_ws,
    float* __restrict__ out_lat)
{
    __shared__ __align__(16) char smem[43008];
    us_t* x_lds = (us_t*)(smem);           // [32][200] (192 used)
    float* h3s  = (float*)(smem);          // [32][132] alias (x dead after A1)
    us_t* h_a   = (us_t*)(smem + 16896);   // [32][136]
    us_t* h_b   = (us_t*)(smem + 25600);   // [32][136]
    us_t* ohl   = (us_t*)(smem + 34304);   // [32][136]

    const int t  = threadIdx.x;
    const int e0 = blockIdx.x * 32;
    const int lane = t & 63, w = t >> 6;

    for (int idx = t; idx < 32 * 24; idx += 256) {
        int ee = idx / 24, i = idx - ee * 24;
        *(uint4*)&x_lds[ee * 200 + i * 8] =
            *(const uint4*)&lnscal_ws[(size_t)(e0 + ee) * 192 + i * 8];
    }
    for (int idx = t; idx < 32 * 32; idx += 256) {
        int ee = idx >> 5, j = idx & 31;
        float4 ov = *(const float4*)&one_hot[(size_t)(e0 + ee) * 128 + j * 4];
        ushort4 s; s.x = f2b(ov.x); s.y = f2b(ov.y); s.z = f2b(ov.z); s.w = f2b(ov.w);
        *(ushort4*)&ohl[ee * 136 + j * 4] = s;
    }
    __syncthreads();

    mlayer<6, true>(x_lds, x_lds, 6, 200, wbase + WO_A1, 192, A1b, h_a, 136, lane, w);
    __syncthreads();
    mlayer<4, true>(h_a, h_a, 4, 136, wbase + WO_A2, 128, A2b, h_b, 136, lane, w);
    __syncthreads();
    mlayer<4, false>(h_b, h_b, 4, 136, wbase + WO_A3, 128, A3b, h_a, 136, lane, w);
    __syncthreads();
    mlayer<8, true>(h_a, ohl, 4, 136, wbase + WO_B1, 256, B1b, h_b, 136, lane, w);
    __syncthreads();
    mlayer<4, true>(h_b, h_b, 4, 136, wbase + WO_B2, 128, B2b, h_a, 136, lane, w);
    __syncthreads();
    // B3 -> f32 h3s
    {
        const int r = lane & 15, g = lane >> 4;
        const int n0 = 2 * w * 16, n1 = n0 + 16;
        f32x4 a00 = {0.f,0.f,0.f,0.f}, a01 = a00, a10 = a00, a11 = a00;
        const us_t* wp0 = wbase + WO_B3 + (size_t)(n0 + r) * 128 + g * 8;
        const us_t* wp1 = wbase + WO_B3 + (size_t)(n1 + r) * 128 + g * 8;
        #pragma unroll
        for (int ks = 0; ks < 4; ++ks) {
            bf16x8 f0 = *(const bf16x8*)(h_a + ks * 32 + r * 136 + g * 8);
            bf16x8 f1 = *(const bf16x8*)(h_a + ks * 32 + (16 + r) * 136 + g * 8);
            bf16x8 b0 = *(const bf16x8*)(wp0 + ks * 32);
            bf16x8 b1 = *(const bf16x8*)(wp1 + ks * 32);
            a00 = MFMA(f0, b0, a00); a01 = MFMA(f0, b1, a01);
            a10 = MFMA(f1, b0, a10); a11 = MFMA(f1, b1, a11);
        }
        float bi0 = B3b[n0 + r], bi1 = B3b[n1 + r];
        #pragma unroll
        for (int i = 0; i < 4; ++i) {
            int eA = g * 4 + i, eB = 16 + g * 4 + i;
            h3s[eA * 132 + n0 + r] = a00[i] + bi0;
            h3s[eA * 132 + n1 + r] = a01[i] + bi1;
            h3s[eB * 132 + n0 + r] = a10[i] + bi0;
            h3s[eB * 132 + n1 + r] = a11[i] + bi1;
        }
    }

    // O-projections (independent of MLP; reads ohl only)
    {
        const int r = lane & 15, g = lane >> 4;
        const int cnt = (w == 3) ? 1 : 2;
        #pragma unroll
        for (int ii = 0; ii < 2; ++ii) {
            if (ii >= cnt) break;
            int nt = (ii == 0) ? w : w + 4;
            const us_t* wb2 = (nt < 4) ? (wbase + WO_O0 + (size_t)nt * 16 * 128)
                            : (nt < 6) ? (wbase + WO_O1 + (size_t)(nt - 4) * 16 * 128)
                                       : (wbase + WO_O2);
            f32x4 c0 = {0.f,0.f,0.f,0.f}, c1 = c0;
            const us_t* wp = wb2 + (size_t)r * 128 + g * 8;
            #pragma unroll
            for (int ks = 0; ks < 4; ++ks) {
                bf16x8 f0 = *(const bf16x8*)(ohl + ks * 32 + r * 136 + g * 8);
                bf16x8 f1 = *(const bf16x8*)(ohl + ks * 32 + (16 + r) * 136 + g * 8);
                bf16x8 b = *(const bf16x8*)(wp + ks * 32);
                c0 = MFMA(f0, b, c0); c1 = MFMA(f1, b, c1);
            }
            int n = nt * 16 + r;
            #pragma unroll
            for (int i = 0; i < 4; ++i) {
                int eA = e0 + g * 4 + i, eB = e0 + 16 + g * 4 + i;
                ohw_ws[(size_t)eA * 112 + n] = f2b(c0[i]);
                ohw_ws[(size_t)eB * 112 + n] = f2b(c1[i]);
            }
        }
    }
    __syncthreads();

    // Latent scatter
    for (int idx = t; idx < 1024; idx += 256) {
        int ee = idx >> 5, c4 = (idx & 31) * 4;
        int ae = active_edges[e0 + ee];
        float cut = cutoff[ae];
        float4 lv = *(const float4*)&latents[(size_t)ae * 128 + c4];
        float4 hv = *(const float4*)&h3s[ee * 132 + c4];
        float4 ov;
        ov.x = C_NEW * cut * hv.x + C_OLD * lv.x;
        ov.y = C_NEW * cut * hv.y + C_OLD * lv.y;
        ov.z = C_NEW * cut * hv.z + C_OLD * lv.z;
        ov.w = C_NEW * cut * hv.w + C_OLD * lv.w;
        *(float4*)&out_lat[(size_t)ae * 128 + c4] = ov;
    }
}

// ============================================================================
// K3: edge_out = (c_old*ef + c_new*ne) * (1 + s*oh), 4 elems/thread
// ============================================================================
__global__ __launch_bounds__(256) void kfin_kernel(
    const float* __restrict__ edge_features, const us_t* __restrict__ ne_ws,
    const us_t* __restrict__ ohw_ws, float* __restrict__ out_edge)
{
    int idx = blockIdx.x * 256 + threadIdx.x;   // over E_ACT*60 float4s
    if (idx >= E_ACT * 60) return;
    int e = idx / 60;
    int c0 = (idx - e * 60) * 4;
    float4 ef = *(const float4*)&edge_features[(size_t)e * 240 + c0];
    ushort4 nv = *(const ushort4*)&ne_ws[(size_t)e * 240 + c0];
    float nef[4] = {b2f(nv.x), b2f(nv.y), b2f(nv.z), b2f(nv.w)};
    float eff[4] = {ef.x, ef.y, ef.z, ef.w};
    float4 ov;
    float* op = &ov.x;
    #pragma unroll
    for (int j = 0; j < 4; ++j) {
        int c = c0 + j;
        int o;
        if (c < 64)       o = c;
        else if (c < 160) o = 64 + (c - 64) / 3;
        else              o = 96 + (c - 160) / 5;
        float ohv = b2f(ohw_ws[(size_t)e * 112 + o]);
        op[j] = (C_OLD * eff[j] + C_NEW * nef[j]) * (1.f + S_OH * ohv);
    }
    *(float4*)&out_edge[(size_t)e * 240 + c0] = ov;
}

// ============================================================================
extern "C" void kernel_launch(void* const* d_in, const int* in_sizes, int n_in,
                              void* d_out, int out_size, void* d_ws, size_t ws_size,
                              hipStream_t stream)
{
    const float* latents  = (const float*)d_in[0];
    const float* node_f   = (const float*)d_in[1];
    const float* edge_f   = (const float*)d_in[2];
    const float* cutoff   = (const float*)d_in[3];
    const float* one_hot  = (const float*)d_in[4];
    const float* wD1      = (const float*)d_in[5];
    const float* wD2      = (const float*)d_in[6];
    const float* W0       = (const float*)d_in[7];
    const float* W1r      = (const float*)d_in[8];
    const float* W1i      = (const float*)d_in[9];
    const float* W2r      = (const float*)d_in[10];
    const float* W2i      = (const float*)d_in[11];
    const float* Gw       = (const float*)d_in[12];
    const float* Gb       = (const float*)d_in[13];
    const float* P0w      = (const float*)d_in[14];
    const float* P0b      = (const float*)d_in[15];
    const float* P1w      = (const float*)d_in[16];
    const float* P2w      = (const float*)d_in[17];
    const float* Ew       = (const float*)d_in[18];
    const float* Eb       = (const float*)d_in[19];
    const float* ln_g     = (const float*)d_in[20];
    const float* ln_b     = (const float*)d_in[21];
    const float* A1       = (const float*)d_in[22];
    const float* A1b      = (const float*)d_in[23];
    const float* A2       = (const float*)d_in[24];
    const float* A2b      = (const float*)d_in[25];
    const float* A3       = (const float*)d_in[26];
    const float* A3b      = (const float*)d_in[27];
    const float* B1       = (const float*)d_in[28];
    const float* B1b      = (const float*)d_in[29];
    const float* B2       = (const float*)d_in[30];
    const float* B2b      = (const float*)d_in[31];
    const float* B3       = (const float*)d_in[32];
    const float* B3b      = (const float*)d_in[33];
    const float* O0       = (const float*)d_in[34];
    const float* O1       = (const float*)d_in[35];
    const float* O2       = (const float*)d_in[36];
    const int* edge_index = (const int*)d_in[37];
    const int* act_e      = (const int*)d_in[38];

    float* out_edge = (float*)d_out;                      // E_ACT*240 f32
    float* out_lat  = out_edge + (size_t)E_ACT * DIR;     // E_TOT*128 f32

    us_t* ne_ws     = (us_t*)d_ws;                                 // E_ACT*240 bf16
    us_t* lnscal_ws = ne_ws + (size_t)E_ACT * DIR;                 // E_ACT*192 bf16
    us_t* ohw_ws    = lnscal_ws + (size_t)E_ACT * 192;             // E_ACT*112 bf16
    us_t* wbase     = ohw_ws + (size_t)E_ACT * 112;                // W_TOTAL bf16

    prep_kernel<<<dim3((W_TOTAL + 255) / 256), dim3(256), 0, stream>>>(
        W0, W1r, W1i, W2r, W2i, Gw, Ew, A1, A2, A3, B1, B2, B3, O0, O1, O2, wbase);

    hipMemcpyAsync(out_lat, latents, (size_t)E_TOT * 128 * sizeof(float),
                   hipMemcpyDeviceToDevice, stream);

    k1_kernel<<<dim3(E_ACT / 16), dim3(256), 0, stream>>>(
        latents, node_f, edge_f, wD1, wD2, Gb, Eb, P0w, P0b, P1w, P2w,
        ln_g, ln_b, edge_index, act_e, wbase, ne_ws, lnscal_ws);

    k2_kernel<<<dim3(E_ACT / 32), dim3(256), 0, stream>>>(
        latents, cutoff, one_hot, A1b, A2b, A3b, B1b, B2b, B3b,
        act_e, wbase, lnscal_ws, ohw_ws, out_lat);

    kfin_kernel<<<dim3((E_ACT * 60 + 255) / 256), dim3(256), 0, stream>>>(
        edge_f, ne_ws, ohw_ws, out_edge);
}

// Round 3
// 1238.766 us; speedup vs baseline: 8.6408x; 1.3622x over previous
//
#include <hip/hip_runtime.h>

typedef unsigned short us_t;
typedef short bf16x8 __attribute__((ext_vector_type(8)));
typedef float f32x4 __attribute__((ext_vector_type(4)));

#define E_ACT 200000
#define E_TOT 250000
#define DIR   240
#define C_OLD 0.8944271909999159f
#define C_NEW 0.4472135954999579f
#define S_OH  0.08838834764831845f   // 1/sqrt(128)

// ---- transposed bf16 weight arena offsets (elements) ----
#define WO_W0   0         // [160][352]
#define WO_W1P  56320     // [48][288]
#define WO_W1M  70144     // [48][288]
#define WO_W2P  83968     // [16][96]
#define WO_W2M  85504     // [16][96]
#define WO_GW   87040     // [224][128]
#define WO_EW   115712    // [112][128]
#define WO_A1   130048    // [128][192]
#define WO_A2   154624    // [128][128]
#define WO_A3   171008    // [128][128]
#define WO_B1   187392    // [128][256]
#define WO_B2   220160    // [128][128]
#define WO_B3   236544    // [128][128]
#define WO_O0   252928    // [64][128]
#define WO_O1   261120    // [32][128]
#define WO_O2   265216    // [16][128]
#define W_TOTAL 267264

__device__ __forceinline__ float b2f(us_t u) { return __uint_as_float(((unsigned)u) << 16); }
__device__ __forceinline__ us_t f2b(float f) {
    unsigned x = __float_as_uint(f);
    return (us_t)((x + 0x7fffu + ((x >> 16) & 1u)) >> 16);   // RNE
}
__device__ __forceinline__ float sigm(float x) { return 1.0f / (1.0f + __expf(-x)); }

#define MFMA(a,b,c) __builtin_amdgcn_mfma_f32_16x16x32_bf16((a),(b),(c),0,0,0)

// ============================================================================
// prep: build transposed/padded bf16 weights in workspace
// ============================================================================
__global__ __launch_bounds__(256) void prep_kernel(
    const float* __restrict__ W0, const float* __restrict__ W1r, const float* __restrict__ W1i,
    const float* __restrict__ W2r, const float* __restrict__ W2i,
    const float* __restrict__ Gw, const float* __restrict__ Ew,
    const float* __restrict__ A1, const float* __restrict__ A2, const float* __restrict__ A3,
    const float* __restrict__ B1, const float* __restrict__ B2, const float* __restrict__ B3,
    const float* __restrict__ O0, const float* __restrict__ O1, const float* __restrict__ O2,
    us_t* __restrict__ wb)
{
    int idx = blockIdx.x * 256 + threadIdx.x;
    if (idx >= W_TOTAL) return;
    float v;
    if (idx < WO_W1P) {                        // W0T [160][352], pad k 336->352
        int r = idx, n = r / 352, k = r % 352;
        v = (k < 336) ? W0[n * 336 + k] : 0.f;
    } else if (idx < WO_W1M) {                 // [W1r | -W1i]  [48][288]
        int r = idx - WO_W1P, n = r / 288, k = r % 288;
        v = (k < 144) ? W1r[n * 144 + k] : -W1i[n * 144 + (k - 144)];
    } else if (idx < WO_W2P) {                 // [W1i | W1r]
        int r = idx - WO_W1M, n = r / 288, k = r % 288;
        v = (k < 144) ? W1i[n * 144 + k] : W1r[n * 144 + (k - 144)];
    } else if (idx < WO_W2M) {                 // [W2r | -W2i]  [16][96]
        int r = idx - WO_W2P, n = r / 96, k = r % 96;
        v = (k < 48) ? W2r[n * 48 + k] : -W2i[n * 48 + (k - 48)];
    } else if (idx < WO_GW) {                  // [W2i | W2r]
        int r = idx - WO_W2M, n = r / 96, k = r % 96;
        v = (k < 48) ? W2i[n * 48 + k] : W2r[n * 48 + (k - 48)];
    } else if (idx < WO_EW) {                  // GwT [224][128]
        int r = idx - WO_GW, n = r / 128, k = r % 128;
        v = Gw[k * 224 + n];
    } else if (idx < WO_A1) {                  // EwT [112][128]
        int r = idx - WO_EW, n = r / 128, k = r % 128;
        v = Ew[k * 112 + n];
    } else if (idx < WO_A2) {                  // A1T [128][192]
        int r = idx - WO_A1, n = r / 192, k = r % 192;
        v = A1[k * 128 + n];
    } else if (idx < WO_A3) {                  // A2T [128][128]
        int r = idx - WO_A2, n = r / 128, k = r % 128;
        v = A2[k * 128 + n];
    } else if (idx < WO_B1) {                  // A3T
        int r = idx - WO_A3, n = r / 128, k = r % 128;
        v = A3[k * 128 + n];
    } else if (idx < WO_B2) {                  // B1T [128][256]
        int r = idx - WO_B1, n = r / 256, k = r % 256;
        v = B1[k * 128 + n];
    } else if (idx < WO_B3) {                  // B2T
        int r = idx - WO_B2, n = r / 128, k = r % 128;
        v = B2[k * 128 + n];
    } else if (idx < WO_O0) {                  // B3T
        int r = idx - WO_B3, n = r / 128, k = r % 128;
        v = B3[k * 128 + n];
    } else if (idx < WO_O1) {                  // O0 [64][128] already N-major
        v = O0[idx - WO_O0];
    } else if (idx < WO_O2) {
        v = O1[idx - WO_O1];
    } else {
        v = O2[idx - WO_O2];
    }
    wb[idx] = f2b(v);
}

// ---- per-wave MFMA tile helpers (A: LDS bf16 rows, B: global bf16 [N][kp]) ----
template<int KS>
__device__ __forceinline__ void gemm2(
    const us_t* __restrict__ act, int as,
    const us_t* __restrict__ wgt, int kp,
    int nt0, int nt1, us_t* __restrict__ out, int os, int lane)
{
    const int r = lane & 15, g = lane >> 4;
    f32x4 acc0 = {0.f,0.f,0.f,0.f}, acc1 = {0.f,0.f,0.f,0.f};
    const us_t* ap  = act + r * as + g * 8;
    const us_t* wp0 = wgt + (size_t)(nt0 * 16 + r) * kp + g * 8;
    const us_t* wp1 = wgt + (size_t)(nt1 * 16 + r) * kp + g * 8;
    #pragma unroll
    for (int ks = 0; ks < KS; ++ks) {
        bf16x8 a  = *(const bf16x8*)(ap  + ks * 32);
        bf16x8 b0 = *(const bf16x8*)(wp0 + ks * 32);
        bf16x8 b1 = *(const bf16x8*)(wp1 + ks * 32);
        acc0 = MFMA(a, b0, acc0);
        acc1 = MFMA(a, b1, acc1);
    }
    #pragma unroll
    for (int i = 0; i < 4; ++i) {
        int e = g * 4 + i;
        out[e * os + nt0 * 16 + r] = f2b(acc0[i]);
        out[e * os + nt1 * 16 + r] = f2b(acc1[i]);
    }
}

template<int KS>
__device__ __forceinline__ void gemm1(
    const us_t* __restrict__ act, int as,
    const us_t* __restrict__ wgt, int kp,
    int nt, us_t* __restrict__ out, int os, int lane)
{
    const int r = lane & 15, g = lane >> 4;
    f32x4 acc = {0.f,0.f,0.f,0.f};
    const us_t* ap = act + r * as + g * 8;
    const us_t* wp = wgt + (size_t)(nt * 16 + r) * kp + g * 8;
    #pragma unroll
    for (int ks = 0; ks < KS; ++ks) {
        bf16x8 a = *(const bf16x8*)(ap + ks * 32);
        bf16x8 b = *(const bf16x8*)(wp + ks * 32);
        acc = MFMA(a, b, acc);
    }
    #pragma unroll
    for (int i = 0; i < 4; ++i) {
        int e = g * 4 + i;
        out[e * os + nt * 16 + r] = f2b(acc[i]);
    }
}

// ---- latent GEMMs: A fetched once from global into registers ----
__device__ __forceinline__ void lat_fetch_a(const float* __restrict__ latents,
                                            const int* __restrict__ aes_l,
                                            int lane, bf16x8 a[4])
{
    const int r = lane & 15, g = lane >> 4;
    const float* lp = latents + (size_t)aes_l[r] * 128 + g * 8;
    #pragma unroll
    for (int ks = 0; ks < 4; ++ks) {
        float4 v0 = *(const float4*)(lp + ks * 32);
        float4 v1 = *(const float4*)(lp + ks * 32 + 4);
        bf16x8 av;
        av[0] = (short)f2b(v0.x); av[1] = (short)f2b(v0.y);
        av[2] = (short)f2b(v0.z); av[3] = (short)f2b(v0.w);
        av[4] = (short)f2b(v1.x); av[5] = (short)f2b(v1.y);
        av[6] = (short)f2b(v1.z); av[7] = (short)f2b(v1.w);
        a[ks] = av;
    }
}

__device__ __forceinline__ void lat_gemm2(const bf16x8 a[4],
    const us_t* __restrict__ wgt, const float* __restrict__ bias,
    int nt0, int nt1, us_t* __restrict__ out, int os, int lane)
{
    const int r = lane & 15, g = lane >> 4;
    f32x4 acc0 = {0.f,0.f,0.f,0.f}, acc1 = {0.f,0.f,0.f,0.f};
    const us_t* wp0 = wgt + (size_t)(nt0 * 16 + r) * 128 + g * 8;
    const us_t* wp1 = wgt + (size_t)(nt1 * 16 + r) * 128 + g * 8;
    #pragma unroll
    for (int ks = 0; ks < 4; ++ks) {
        bf16x8 b0 = *(const bf16x8*)(wp0 + ks * 32);
        bf16x8 b1 = *(const bf16x8*)(wp1 + ks * 32);
        acc0 = MFMA(a[ks], b0, acc0);
        acc1 = MFMA(a[ks], b1, acc1);
    }
    float bi0 = bias[nt0 * 16 + r], bi1 = bias[nt1 * 16 + r];
    #pragma unroll
    for (int i = 0; i < 4; ++i) {
        int e = g * 4 + i;
        out[e * os + nt0 * 16 + r] = f2b(acc0[i] + bi0);
        out[e * os + nt1 * 16 + r] = f2b(acc1[i] + bi1);
    }
}

__device__ __forceinline__ void lat_gemm1(const bf16x8 a[4],
    const us_t* __restrict__ wgt, const float* __restrict__ bias,
    int nt, us_t* __restrict__ out, int os, int lane)
{
    const int r = lane & 15, g = lane >> 4;
    f32x4 acc = {0.f,0.f,0.f,0.f};
    const us_t* wp = wgt + (size_t)(nt * 16 + r) * 128 + g * 8;
    #pragma unroll
    for (int ks = 0; ks < 4; ++ks) {
        bf16x8 b = *(const bf16x8*)(wp + ks * 32);
        acc = MFMA(a[ks], b, acc);
    }
    float bi = bias[nt * 16 + r];
    #pragma unroll
    for (int i = 0; i < 4; ++i) {
        int e = g * 4 + i;
        out[e * os + nt * 16 + r] = f2b(acc[i] + bi);
    }
}

// ============================================================================
// K1: register gather + shfl-broadcast rotations + MFMA stage-1 GEMMs
//     + y-build/D^T + P0/P1/P2 + LN.  16 edges / 256-thread block (4 waves).
//     LDS 47.6KB -> 3 blocks/CU.
// ============================================================================
__global__ __launch_bounds__(256, 3) void k1_kernel(
    const float* __restrict__ latents,
    const float* __restrict__ node_features,
    const float* __restrict__ edge_features,
    const float* __restrict__ wD1,
    const float* __restrict__ wD2,
    const float* __restrict__ Gb,  const float* __restrict__ Eb,
    const float* __restrict__ P0w, const float* __restrict__ P0b,
    const float* __restrict__ P1w, const float* __restrict__ P2w,
    const float* __restrict__ ln_g, const float* __restrict__ ln_b,
    const int* __restrict__ edge_index, const int* __restrict__ active_edges,
    const us_t* __restrict__ wbase,
    us_t* __restrict__ ne_ws, us_t* __restrict__ lnscal_ws)
{
    __shared__ __align__(16) char smem[48704];
    // activations (bf16), read in phase B
    us_t* in0s  = (us_t*)(smem);            // [16][360] K=352 (W0)
    us_t* cact1 = (us_t*)(smem + 11520);    // [16][296] [ip1|im1] K=288
    us_t* cact2 = (us_t*)(smem + 20992);    // [16][104] [r24|r20] K=96
    float* D1l  = (float*)(smem + 24320);   // [16][12]
    float* D2l  = (float*)(smem + 25088);   // [16][28]
    int*   aes  = (int*)(smem + 26880);     // [16]
    // GEMM raw outputs (bf16)
    us_t* om0r  = (us_t*)(smem + 26944);    // [16][168] raw o_m0 (160)
    us_t* cp1r  = (us_t*)(smem + 32320);    // [16][56]  raw op1 (48)
    us_t* cn1r  = (us_t*)(smem + 34112);    // [16][56]  raw on1
    us_t* cp2r  = (us_t*)(smem + 35904);    // [16][24]  raw op2 (16)
    us_t* cn2r  = (us_t*)(smem + 36672);    // [16][24]  raw on2
    us_t* gl    = (us_t*)(smem + 37440);    // [16][232] g (224)
    us_t* wl    = (us_t*)(smem + 44864);    // [16][120] w (112)
    // phase-C aliases (activation region is dead after phase B)
    float* z1l  = (float*)(smem);           // [16][100] m-major: i*32+u
    float* z2l  = (float*)(smem + 6400);    // [16][84]  m-major: i*16+u
    float* z0l  = (float*)(smem + 11776);   // [16][68]
    float* P1s  = (float*)(smem + 16128);   // [32][36] f32 (pad 36)
    float* P2s  = (float*)(smem + 20736);   // [16][20] f32 (pad 20)

    const int t  = threadIdx.x;
    const int e0 = blockIdx.x * 16;

    // ---------------- Phase A: register gather + rotate -> LDS activations ----
    {
        const int e = t >> 4, l = t & 15;
        const int eg = e0 + e;
        const int ae = active_edges[eg];
        const int ec = edge_index[ae];
        const int en = edge_index[E_TOT + ae];
        if (l == 0) aes[e] = ae;

        float v1  = (l < 9) ? wD1[(size_t)eg * 9 + l] : 0.f;
        float v2a = wD2[(size_t)eg * 25 + l];
        float v2b = (l < 9) ? wD2[(size_t)eg * 25 + 16 + l] : 0.f;
        if (l < 9) D1l[e * 12 + l] = v1;               // for phase C1
        D2l[e * 28 + l] = v2a;
        if (l < 9) D2l[e * 28 + 16 + l] = v2b;

        float d1[9], d2[25];
        #pragma unroll
        for (int i = 0; i < 9; ++i)  d1[i] = __shfl(v1, i, 16);
        #pragma unroll
        for (int i = 0; i < 16; ++i) d2[i] = __shfl(v2a, i, 16);
        #pragma unroll
        for (int i = 0; i < 9; ++i)  d2[16 + i] = __shfl(v2b, i, 16);

        const float* pc = node_features + (size_t)ec * DIR;
        const float* pe = edge_features + (size_t)eg * DIR;
        const float* pn = node_features + (size_t)en * DIR;
        us_t* in0 = in0s + e * 360;
        us_t* c1  = cact1 + e * 296;
        us_t* c2  = cact2 + e * 104;

        #pragma unroll
        for (int j = 0; j < 4; ++j) {
            int i = l + 16 * j;
            in0[i]       = f2b(pc[i]);
            in0[64 + i]  = f2b(pe[i]);
            in0[128 + i] = f2b(pn[i]);
        }
        in0[336 + l] = 0;   // zero K-pad 336..351

        #pragma unroll
        for (int jj = 0; jj < 6; ++jj) {
            int u = l + 16 * jj;
            int uu = u & 31;
            const float* sp = (u < 32 ? pc : (u < 64 ? pe : pn)) + 64 + uu * 3;
            float x0 = sp[0], x1 = sp[1], x2 = sp[2];
            float r0 = d1[0] * x0 + d1[1] * x1 + d1[2] * x2;
            float r1 = d1[3] * x0 + d1[4] * x1 + d1[5] * x2;
            float r2 = d1[6] * x0 + d1[7] * x1 + d1[8] * x2;
            c1[144 + u]  = f2b(r0);   // im1 part 1
            in0[192 + u] = f2b(r1);
            c1[u]        = f2b(r2);   // ip1 part 1
        }
        #pragma unroll
        for (int jj = 0; jj < 3; ++jj) {
            int u = l + 16 * jj;
            int uu = u & 15;
            const float* sp = (u < 16 ? pc : (u < 32 ? pe : pn)) + 160 + uu * 5;
            float x0 = sp[0], x1 = sp[1], x2 = sp[2], x3 = sp[3], x4 = sp[4];
            float r[5];
            #pragma unroll
            for (int i = 0; i < 5; ++i)
                r[i] = d2[i * 5 + 0] * x0 + d2[i * 5 + 1] * x1 + d2[i * 5 + 2] * x2
                     + d2[i * 5 + 3] * x3 + d2[i * 5 + 4] * x4;
            c2[48 + u]   = f2b(r[0]);  // r20
            c1[240 + u]  = f2b(r[1]);  // im1 part 2
            in0[288 + u] = f2b(r[2]);
            c1[96 + u]   = f2b(r[3]);  // ip1 part 2
            c2[u]        = f2b(r[4]);  // r24
        }
    }
    __syncthreads();

    // ---------------- Phase B: MFMA GEMMs (per-wave static tile lists) --------
    {
        const int lane = t & 63, w = t >> 6;
        if (w == 0) {
            gemm2<11>(in0s, 360, wbase + WO_W0, 352, 0, 1, om0r, 168, lane);
            gemm2<11>(in0s, 360, wbase + WO_W0, 352, 2, 3, om0r, 168, lane);
            gemm2<11>(in0s, 360, wbase + WO_W0, 352, 4, 5, om0r, 168, lane);
        } else if (w == 1) {
            bf16x8 a[4]; lat_fetch_a(latents, aes, lane, a);
            gemm2<11>(in0s, 360, wbase + WO_W0, 352, 6, 7, om0r, 168, lane);
            gemm2<11>(in0s, 360, wbase + WO_W0, 352, 8, 9, om0r, 168, lane);
            gemm1<3>(cact2, 104, wbase + WO_W2P, 96, 0, cp2r, 24, lane);
            gemm1<3>(cact2, 104, wbase + WO_W2M, 96, 0, cn2r, 24, lane);
            lat_gemm2(a, wbase + WO_EW, Eb, 0, 1, wl, 120, lane);
        } else if (w == 2) {
            bf16x8 a[4]; lat_fetch_a(latents, aes, lane, a);
            gemm2<9>(cact1, 296, wbase + WO_W1P, 288, 0, 1, cp1r, 56, lane);
            gemm1<9>(cact1, 296, wbase + WO_W1P, 288, 2, cp1r, 56, lane);
            gemm2<9>(cact1, 296, wbase + WO_W1M, 288, 0, 1, cn1r, 56, lane);
            gemm1<9>(cact1, 296, wbase + WO_W1M, 288, 2, cn1r, 56, lane);
            lat_gemm2(a, wbase + WO_EW, Eb, 2, 3, wl, 120, lane);
            lat_gemm1(a, wbase + WO_EW, Eb, 4, wl, 120, lane);
        } else {
            bf16x8 a[4]; lat_fetch_a(latents, aes, lane, a);
            #pragma unroll
            for (int p = 0; p < 7; ++p)
                lat_gemm2(a, wbase + WO_GW, Gb, 2 * p, 2 * p + 1, gl, 232, lane);
            lat_gemm2(a, wbase + WO_EW, Eb, 5, 6, wl, 120, lane);
        }
    }
    __syncthreads();

    // ---------------- Phase C1: gate + y-build + D^T rotations + silu ---------
    {
        const int e = t >> 4, l = t & 15;
        const float* D1e = D1l + e * 12;
        const float* D2e = D2l + e * 28;
        #pragma unroll
        for (int uu = 0; uu < 2; ++uu) {
            int u = l + uu * 16;
            float g1 = b2f(gl[e * 232 + 160 + u]);
            float j0 = b2f(cn1r[e * 56 + u]) * g1;
            float j1 = b2f(om0r[e * 168 + 112 + u]) * b2f(gl[e * 232 + 112 + u]);
            float j2 = b2f(cp1r[e * 56 + u]) * g1;
            float gate = sigm(b2f(om0r[e * 168 + 64 + u]) * b2f(gl[e * 232 + 64 + u]));
            #pragma unroll
            for (int i = 0; i < 3; ++i) {
                float yr = D1e[0 * 3 + i] * j0 + D1e[1 * 3 + i] * j1 + D1e[2 * 3 + i] * j2;
                z1l[e * 100 + i * 32 + u] = yr * gate;    // m-major
            }
        }
        {
            int u = l;
            float g2  = b2f(gl[e * 232 + 208 + u]);
            float g1b = b2f(gl[e * 232 + 192 + u]);
            float j0 = b2f(cn2r[e * 24 + u]) * g2;
            float j1 = b2f(cn1r[e * 56 + 32 + u]) * g1b;
            float j2 = b2f(om0r[e * 168 + 144 + u]) * b2f(gl[e * 232 + 144 + u]);
            float j3 = b2f(cp1r[e * 56 + 32 + u]) * g1b;
            float j4 = b2f(cp2r[e * 24 + u]) * g2;
            float gate = sigm(b2f(om0r[e * 168 + 96 + u]) * b2f(gl[e * 232 + 96 + u]));
            #pragma unroll
            for (int i = 0; i < 5; ++i) {
                float yr = D2e[0 * 5 + i] * j0 + D2e[1 * 5 + i] * j1 + D2e[2 * 5 + i] * j2
                         + D2e[3 * 5 + i] * j3 + D2e[4 * 5 + i] * j4;
                z2l[e * 84 + i * 16 + u] = yr * gate;     // m-major
            }
        }
        #pragma unroll
        for (int ii = 0; ii < 4; ++ii) {
            int c = l + 16 * ii;
            float v = b2f(om0r[e * 168 + c]) * b2f(gl[e * 232 + c]);
            z0l[e * 68 + c] = v * sigm(v);
        }
        // stage P1/P2 into LDS (bank-padded)
        for (int i = t; i < 1024; i += 256) P1s[(i >> 5) * 36 + (i & 31)] = P1w[i];
        if (t < 256) P2s[(t >> 4) * 20 + (t & 15)] = P2w[t];
    }
    __syncthreads();

    // ---------------- Phase C2: P0/P1/P2 + w-scale + scalars + LayerNorm ------
    {
        const int e = t >> 4, l = t & 15;
        const int eg = e0 + e;
        #pragma unroll
        for (int j = 0; j < 4; ++j) {
            int n = l + 16 * j;
            float acc = 0.f;
            for (int k = 0; k < 64; k += 4) {
                float4 zv = *(const float4*)&z0l[e * 68 + k];
                float4 pw = *(const float4*)&P0w[n * 64 + k];
                acc += zv.x * pw.x + zv.y * pw.y + zv.z * pw.z + zv.w * pw.w;
            }
            float z0p = acc * 0.125f + P0b[n];
            lnscal_ws[(size_t)eg * 192 + 128 + n] = f2b(z0p);
            ne_ws[(size_t)eg * 240 + n] = f2b(z0p * b2f(wl[e * 120 + n]));
        }
        #pragma unroll
        for (int uu = 0; uu < 2; ++uu) {
            int u = l + uu * 16;
            float wv = b2f(wl[e * 120 + 64 + u]);
            float a0 = 0.f, a1 = 0.f, a2 = 0.f;
            #pragma unroll
            for (int v4 = 0; v4 < 8; ++v4) {
                float4 pw = *(const float4*)&P1s[u * 36 + v4 * 4];
                float4 zv0 = *(const float4*)&z1l[e * 100 + 0 * 32 + v4 * 4];
                float4 zv1 = *(const float4*)&z1l[e * 100 + 1 * 32 + v4 * 4];
                float4 zv2 = *(const float4*)&z1l[e * 100 + 2 * 32 + v4 * 4];
                a0 += pw.x * zv0.x + pw.y * zv0.y + pw.z * zv0.z + pw.w * zv0.w;
                a1 += pw.x * zv1.x + pw.y * zv1.y + pw.z * zv1.z + pw.w * zv1.w;
                a2 += pw.x * zv2.x + pw.y * zv2.y + pw.z * zv2.z + pw.w * zv2.w;
            }
            const float sc1 = 0.17677669529663687f;
            ne_ws[(size_t)eg * 240 + 64 + u * 3 + 0] = f2b(a0 * sc1 * wv);
            ne_ws[(size_t)eg * 240 + 64 + u * 3 + 1] = f2b(a1 * sc1 * wv);
            ne_ws[(size_t)eg * 240 + 64 + u * 3 + 2] = f2b(a2 * sc1 * wv);
        }
        {
            int u = l;
            float wv = b2f(wl[e * 120 + 96 + u]);
            float a[5] = {0.f, 0.f, 0.f, 0.f, 0.f};
            #pragma unroll
            for (int v4 = 0; v4 < 4; ++v4) {
                float4 pw = *(const float4*)&P2s[u * 20 + v4 * 4];
                #pragma unroll
                for (int m = 0; m < 5; ++m) {
                    float4 zv = *(const float4*)&z2l[e * 84 + m * 16 + v4 * 4];
                    a[m] += pw.x * zv.x + pw.y * zv.y + pw.z * zv.z + pw.w * zv.w;
                }
            }
            #pragma unroll
            for (int m = 0; m < 5; ++m)
                ne_ws[(size_t)eg * 240 + 160 + u * 5 + m] = f2b(a[m] * 0.25f * wv);
        }
        // LayerNorm from global latents (f32)
        const int ae = aes[e];
        const float* lp = latents + (size_t)ae * 128 + l * 8;
        float4 va = *(const float4*)lp;
        float4 vb = *(const float4*)(lp + 4);
        float xs[8] = {va.x, va.y, va.z, va.w, vb.x, vb.y, vb.z, vb.w};
        float s1 = 0.f, s2 = 0.f;
        #pragma unroll
        for (int i = 0; i < 8; ++i) { s1 += xs[i]; s2 += xs[i] * xs[i]; }
        #pragma unroll
        for (int off = 1; off < 16; off <<= 1) {
            s1 += __shfl_xor(s1, off, 16);
            s2 += __shfl_xor(s2, off, 16);
        }
        float mu  = s1 * (1.f / 128.f);
        float var = s2 * (1.f / 128.f) - mu * mu;
        float rstd = rsqrtf(var + 1e-5f);
        #pragma unroll
        for (int i = 0; i < 8; ++i) {
            int li = l * 8 + i;
            float v = (xs[i] - mu) * rstd * ln_g[li] + ln_b[li];
            lnscal_ws[(size_t)eg * 192 + li] = f2b(v);
        }
    }
}

// ============================================================================
// K2: MFMA MLP chain + O-projections + latent scatter. 32 edges / 4 waves.
// ============================================================================
template<int KS, bool SILU>
__device__ __forceinline__ void mlayer(
    const us_t* __restrict__ actA, const us_t* __restrict__ actB, int split, int as,
    const us_t* __restrict__ wgt, int kp, const float* __restrict__ bias,
    us_t* __restrict__ out, int os, int lane, int w)
{
    const int r = lane & 15, g = lane >> 4;
    const int n0 = 2 * w * 16, n1 = n0 + 16;
    f32x4 a00 = {0.f,0.f,0.f,0.f}, a01 = a00, a10 = a00, a11 = a00;
    const us_t* wp0 = wgt + (size_t)(n0 + r) * kp + g * 8;
    const us_t* wp1 = wgt + (size_t)(n1 + r) * kp + g * 8;
    #pragma unroll
    for (int ks = 0; ks < KS; ++ks) {
        const us_t* ab = (ks < split) ? (actA + ks * 32) : (actB + (ks - split) * 32);
        bf16x8 f0 = *(const bf16x8*)(ab + r * as + g * 8);
        bf16x8 f1 = *(const bf16x8*)(ab + (16 + r) * as + g * 8);
        bf16x8 b0 = *(const bf16x8*)(wp0 + ks * 32);
        bf16x8 b1 = *(const bf16x8*)(wp1 + ks * 32);
        a00 = MFMA(f0, b0, a00); a01 = MFMA(f0, b1, a01);
        a10 = MFMA(f1, b0, a10); a11 = MFMA(f1, b1, a11);
    }
    float bi0 = bias[n0 + r], bi1 = bias[n1 + r];
    #pragma unroll
    for (int i = 0; i < 4; ++i) {
        int eA = g * 4 + i, eB = 16 + g * 4 + i;
        float v;
        v = a00[i] + bi0; if (SILU) v *= sigm(v); out[eA * os + n0 + r] = f2b(v);
        v = a01[i] + bi1; if (SILU) v *= sigm(v); out[eA * os + n1 + r] = f2b(v);
        v = a10[i] + bi0; if (SILU) v *= sigm(v); out[eB * os + n0 + r] = f2b(v);
        v = a11[i] + bi1; if (SILU) v *= sigm(v); out[eB * os + n1 + r] = f2b(v);
    }
}

__global__ __launch_bounds__(256) void k2_kernel(
    const float* __restrict__ latents, const float* __restrict__ cutoff,
    const float* __restrict__ one_hot,
    const float* __restrict__ A1b, const float* __restrict__ A2b, const float* __restrict__ A3b,
    const float* __restrict__ B1b, const float* __restrict__ B2b, const float* __restrict__ B3b,
    const int* __restrict__ active_edges,
    const us_t* __restrict__ wbase,
    const us_t* __restrict__ lnscal_ws, us_t* __restrict__ ohw_ws,
    float* __restrict__ out_lat)
{
    __shared__ __align__(16) char smem[43008];
    us_t* x_lds = (us_t*)(smem);           // [32][200] (192 used)
    float* h3s  = (float*)(smem);          // [32][132] alias (x dead after A1)
    us_t* h_a   = (us_t*)(smem + 16896);   // [32][136]
    us_t* h_b   = (us_t*)(smem + 25600);   // [32][136]
    us_t* ohl   = (us_t*)(smem + 34304);   // [32][136]

    const int t  = threadIdx.x;
    const int e0 = blockIdx.x * 32;
    const int lane = t & 63, w = t >> 6;

    for (int idx = t; idx < 32 * 24; idx += 256) {
        int ee = idx / 24, i = idx - ee * 24;
        *(uint4*)&x_lds[ee * 200 + i * 8] =
            *(const uint4*)&lnscal_ws[(size_t)(e0 + ee) * 192 + i * 8];
    }
    for (int idx = t; idx < 32 * 32; idx += 256) {
        int ee = idx >> 5, j = idx & 31;
        float4 ov = *(const float4*)&one_hot[(size_t)(e0 + ee) * 128 + j * 4];
        ushort4 s; s.x = f2b(ov.x); s.y = f2b(ov.y); s.z = f2b(ov.z); s.w = f2b(ov.w);
        *(ushort4*)&ohl[ee * 136 + j * 4] = s;
    }
    __syncthreads();

    mlayer<6, true>(x_lds, x_lds, 6, 200, wbase + WO_A1, 192, A1b, h_a, 136, lane, w);
    __syncthreads();
    mlayer<4, true>(h_a, h_a, 4, 136, wbase + WO_A2, 128, A2b, h_b, 136, lane, w);
    __syncthreads();
    mlayer<4, false>(h_b, h_b, 4, 136, wbase + WO_A3, 128, A3b, h_a, 136, lane, w);
    __syncthreads();
    mlayer<8, true>(h_a, ohl, 4, 136, wbase + WO_B1, 256, B1b, h_b, 136, lane, w);
    __syncthreads();
    mlayer<4, true>(h_b, h_b, 4, 136, wbase + WO_B2, 128, B2b, h_a, 136, lane, w);
    __syncthreads();
    // B3 -> f32 h3s
    {
        const int r = lane & 15, g = lane >> 4;
        const int n0 = 2 * w * 16, n1 = n0 + 16;
        f32x4 a00 = {0.f,0.f,0.f,0.f}, a01 = a00, a10 = a00, a11 = a00;
        const us_t* wp0 = wbase + WO_B3 + (size_t)(n0 + r) * 128 + g * 8;
        const us_t* wp1 = wbase + WO_B3 + (size_t)(n1 + r) * 128 + g * 8;
        #pragma unroll
        for (int ks = 0; ks < 4; ++ks) {
            bf16x8 f0 = *(const bf16x8*)(h_a + ks * 32 + r * 136 + g * 8);
            bf16x8 f1 = *(const bf16x8*)(h_a + ks * 32 + (16 + r) * 136 + g * 8);
            bf16x8 b0 = *(const bf16x8*)(wp0 + ks * 32);
            bf16x8 b1 = *(const bf16x8*)(wp1 + ks * 32);
            a00 = MFMA(f0, b0, a00); a01 = MFMA(f0, b1, a01);
            a10 = MFMA(f1, b0, a10); a11 = MFMA(f1, b1, a11);
        }
        float bi0 = B3b[n0 + r], bi1 = B3b[n1 + r];
        #pragma unroll
        for (int i = 0; i < 4; ++i) {
            int eA = g * 4 + i, eB = 16 + g * 4 + i;
            h3s[eA * 132 + n0 + r] = a00[i] + bi0;
            h3s[eA * 132 + n1 + r] = a01[i] + bi1;
            h3s[eB * 132 + n0 + r] = a10[i] + bi0;
            h3s[eB * 132 + n1 + r] = a11[i] + bi1;
        }
    }

    // O-projections (independent of MLP; reads ohl only)
    {
        const int r = lane & 15, g = lane >> 4;
        const int cnt = (w == 3) ? 1 : 2;
        #pragma unroll
        for (int ii = 0; ii < 2; ++ii) {
            if (ii >= cnt) break;
            int nt = (ii == 0) ? w : w + 4;
            const us_t* wb2 = (nt < 4) ? (wbase + WO_O0 + (size_t)nt * 16 * 128)
                            : (nt < 6) ? (wbase + WO_O1 + (size_t)(nt - 4) * 16 * 128)
                                       : (wbase + WO_O2);
            f32x4 c0 = {0.f,0.f,0.f,0.f}, c1 = c0;
            const us_t* wp = wb2 + (size_t)r * 128 + g * 8;
            #pragma unroll
            for (int ks = 0; ks < 4; ++ks) {
                bf16x8 f0 = *(const bf16x8*)(ohl + ks * 32 + r * 136 + g * 8);
                bf16x8 f1 = *(const bf16x8*)(ohl + ks * 32 + (16 + r) * 136 + g * 8);
                bf16x8 b = *(const bf16x8*)(wp + ks * 32);
                c0 = MFMA(f0, b, c0); c1 = MFMA(f1, b, c1);
            }
            int n = nt * 16 + r;
            #pragma unroll
            for (int i = 0; i < 4; ++i) {
                int eA = e0 + g * 4 + i, eB = e0 + 16 + g * 4 + i;
                ohw_ws[(size_t)eA * 112 + n] = f2b(c0[i]);
                ohw_ws[(size_t)eB * 112 + n] = f2b(c1[i]);
            }
        }
    }
    __syncthreads();

    // Latent scatter
    for (int idx = t; idx < 1024; idx += 256) {
        int ee = idx >> 5, c4 = (idx & 31) * 4;
        int ae = active_edges[e0 + ee];
        float cut = cutoff[ae];
        float4 lv = *(const float4*)&latents[(size_t)ae * 128 + c4];
        float4 hv = *(const float4*)&h3s[ee * 132 + c4];
        float4 ov;
        ov.x = C_NEW * cut * hv.x + C_OLD * lv.x;
        ov.y = C_NEW * cut * hv.y + C_OLD * lv.y;
        ov.z = C_NEW * cut * hv.z + C_OLD * lv.z;
        ov.w = C_NEW * cut * hv.w + C_OLD * lv.w;
        *(float4*)&out_lat[(size_t)ae * 128 + c4] = ov;
    }
}

// ============================================================================
// K3: edge_out = (c_old*ef + c_new*ne) * (1 + s*oh), 4 elems/thread
// ============================================================================
__global__ __launch_bounds__(256) void kfin_kernel(
    const float* __restrict__ edge_features, const us_t* __restrict__ ne_ws,
    const us_t* __restrict__ ohw_ws, float* __restrict__ out_edge)
{
    int idx = blockIdx.x * 256 + threadIdx.x;   // over E_ACT*60 float4s
    if (idx >= E_ACT * 60) return;
    int e = idx / 60;
    int c0 = (idx - e * 60) * 4;
    float4 ef = *(const float4*)&edge_features[(size_t)e * 240 + c0];
    ushort4 nv = *(const ushort4*)&ne_ws[(size_t)e * 240 + c0];
    float nef[4] = {b2f(nv.x), b2f(nv.y), b2f(nv.z), b2f(nv.w)};
    float eff[4] = {ef.x, ef.y, ef.z, ef.w};
    float4 ov;
    float* op = &ov.x;
    #pragma unroll
    for (int j = 0; j < 4; ++j) {
        int c = c0 + j;
        int o;
        if (c < 64)       o = c;
        else if (c < 160) o = 64 + (c - 64) / 3;
        else              o = 96 + (c - 160) / 5;
        float ohv = b2f(ohw_ws[(size_t)e * 112 + o]);
        op[j] = (C_OLD * eff[j] + C_NEW * nef[j]) * (1.f + S_OH * ohv);
    }
    *(float4*)&out_edge[(size_t)e * 240 + c0] = ov;
}

// ============================================================================
extern "C" void kernel_launch(void* const* d_in, const int* in_sizes, int n_in,
                              void* d_out, int out_size, void* d_ws, size_t ws_size,
                              hipStream_t stream)
{
    const float* latents  = (const float*)d_in[0];
    const float* node_f   = (const float*)d_in[1];
    const float* edge_f   = (const float*)d_in[2];
    const float* cutoff   = (const float*)d_in[3];
    const float* one_hot  = (const float*)d_in[4];
    const float* wD1      = (const float*)d_in[5];
    const float* wD2      = (const float*)d_in[6];
    const float* W0       = (const float*)d_in[7];
    const float* W1r      = (const float*)d_in[8];
    const float* W1i      = (const float*)d_in[9];
    const float* W2r      = (const float*)d_in[10];
    const float* W2i      = (const float*)d_in[11];
    const float* Gw       = (const float*)d_in[12];
    const float* Gb       = (const float*)d_in[13];
    const float* P0w      = (const float*)d_in[14];
    const float* P0b      = (const float*)d_in[15];
    const float* P1w      = (const float*)d_in[16];
    const float* P2w      = (const float*)d_in[17];
    const float* Ew       = (const float*)d_in[18];
    const float* Eb       = (const float*)d_in[19];
    const float* ln_g     = (const float*)d_in[20];
    const float* ln_b     = (const float*)d_in[21];
    const float* A1       = (const float*)d_in[22];
    const float* A1b      = (const float*)d_in[23];
    const float* A2       = (const float*)d_in[24];
    const float* A2b      = (const float*)d_in[25];
    const float* A3       = (const float*)d_in[26];
    const float* A3b      = (const float*)d_in[27];
    const float* B1       = (const float*)d_in[28];
    const float* B1b      = (const float*)d_in[29];
    const float* B2       = (const float*)d_in[30];
    const float* B2b      = (const float*)d_in[31];
    const float* B3       = (const float*)d_in[32];
    const float* B3b      = (const float*)d_in[33];
    const float* O0       = (const float*)d_in[34];
    const float* O1       = (const float*)d_in[35];
    const float* O2       = (const float*)d_in[36];
    const int* edge_index = (const int*)d_in[37];
    const int* act_e      = (const int*)d_in[38];

    float* out_edge = (float*)d_out;                      // E_ACT*240 f32
    float* out_lat  = out_edge + (size_t)E_ACT * DIR;     // E_TOT*128 f32

    us_t* ne_ws     = (us_t*)d_ws;                                 // E_ACT*240 bf16
    us_t* lnscal_ws = ne_ws + (size_t)E_ACT * DIR;                 // E_ACT*192 bf16
    us_t* ohw_ws    = lnscal_ws + (size_t)E_ACT * 192;             // E_ACT*112 bf16
    us_t* wbase     = ohw_ws + (size_t)E_ACT * 112;                // W_TOTAL bf16

    prep_kernel<<<dim3((W_TOTAL + 255) / 256), dim3(256), 0, stream>>>(
        W0, W1r, W1i, W2r, W2i, Gw, Ew, A1, A2, A3, B1, B2, B3, O0, O1, O2, wbase);

    hipMemcpyAsync(out_lat, latents, (size_t)E_TOT * 128 * sizeof(float),
                   hipMemcpyDeviceToDevice, stream);

    k1_kernel<<<dim3(E_ACT / 16), dim3(256), 0, stream>>>(
        latents, node_f, edge_f, wD1, wD2, Gb, Eb, P0w, P0b, P1w, P2w,
        ln_g, ln_b, edge_index, act_e, wbase, ne_ws, lnscal_ws);

    k2_kernel<<<dim3(E_ACT / 32), dim3(256), 0, stream>>>(
        latents, cutoff, one_hot, A1b, A2b, A3b, B1b, B2b, B3b,
        act_e, wbase, lnscal_ws, ohw_ws, out_lat);

    kfin_kernel<<<dim3((E_ACT * 60 + 255) / 256), dim3(256), 0, stream>>>(
        edge_f, ne_ws, ohw_ws, out_edge);
}